// Round 15
// baseline (267.445 us; speedup 1.0000x reference)
//
#include <hip/hip_runtime.h>

#define BLKE 524288      // 128*64*64
#define VOLE 4194304     // 256*128*128
#define TCROP 2097152    // 128*128*128 (t<128 compact complex volume)
#define PI2 6.283185307179586476925286766559

__device__ __forceinline__ float2 cmulf(float2 a, float2 b){
  return make_float2(a.x*b.x - a.y*b.y, a.x*b.y + a.y*b.x);
}
__device__ __forceinline__ float2 cadd(float2 a, float2 b){
  return make_float2(a.x+b.x, a.y+b.y);
}
__device__ __forceinline__ float2 csub(float2 a, float2 b){
  return make_float2(a.x-b.x, a.y-b.y);
}
__device__ __forceinline__ float waveSum(float v){
  #pragma unroll
  for (int o=32;o;o>>=1) v += __shfl_xor(v,o);
  return v;
}
__device__ __forceinline__ float waveMaxf(float v){
  #pragma unroll
  for (int o=32;o;o>>=1) v = fmaxf(v,__shfl_xor(v,o));
  return v;
}
__device__ __forceinline__ float waveMinf(float v){
  #pragma unroll
  for (int o=32;o;o>>=1) v = fminf(v,__shfl_xor(v,o));
  return v;
}

// Reduce pA[kappa][256][5] redundantly (identical FP order in every block).
__device__ __forceinline__ void bcastReduce5(const float* __restrict__ pA, int kap,
    float& sum, float& mnl, float& mxl, float& mnh, float& mxh, float* sm /*>=20*/){
  int tid = threadIdx.x;
  const float* q = pA + kap*1280 + tid*5;
  float s = q[0], a = q[1], b = q[2], c = q[3], d = q[4];
  s = waveSum(s); a = waveMinf(a); b = waveMaxf(b); c = waveMinf(c); d = waveMaxf(d);
  if ((tid&63)==0){ int w = tid>>6; sm[w]=s; sm[4+w]=a; sm[8+w]=b; sm[12+w]=c; sm[16+w]=d; }
  __syncthreads();
  sum = sm[0]+sm[1]+sm[2]+sm[3];
  mnl = fminf(fminf(sm[4],sm[5]),fminf(sm[6],sm[7]));
  mxl = fmaxf(fmaxf(sm[8],sm[9]),fmaxf(sm[10],sm[11]));
  mnh = fminf(fminf(sm[12],sm[13]),fminf(sm[14],sm[15]));
  mxh = fmaxf(fmaxf(sm[16],sm[17]),fmaxf(sm[18],sm[19]));
}

__device__ __forceinline__ float bcastSum256(const float* __restrict__ p, float* sm /*>=4*/){
  int tid = threadIdx.x;
  float s = waveSum(p[tid]);
  if ((tid&63)==0) sm[tid>>6] = s;
  __syncthreads();
  return sm[0]+sm[1]+sm[2]+sm[3];
}

// ============ D1: attention pass A (0..511) || kM (512..639) || tables (640) =
__global__ void __launch_bounds__(256) kD1(const float* __restrict__ mtx,
                                           const float* __restrict__ wave,
                                           float* __restrict__ M,
                                           const float* __restrict__ Kr,
                                           const float* __restrict__ Ki,
                                           float* __restrict__ Lw, float* __restrict__ Hw,
                                           float* __restrict__ pA,
                                           float2* __restrict__ twF,
                                           float2* __restrict__ twD,
                                           float2* __restrict__ twI){
  __shared__ float spe[128];
  __shared__ float sm[20];
  int bid = blockIdx.x;
  int tid = threadIdx.x;
  if (bid < 512){
    int kap = bid >> 8, bx = bid & 255;
    const float* K = kap ? Ki : Kr;
    if (tid < 128) spe[tid] = sinf((float)tid);
    __syncthreads();
    float sum=0.f, mnl=3.4e38f, mxl=-3.4e38f, mnh=3.4e38f, mxh=-3.4e38f;
    int base = bx*256 + tid;
    #pragma unroll
    for (int it = 0; it < 8; it++){
      int e = base + it*65536;
      int tau = e >> 12, rem = e & 4095, eta = rem >> 6, om = rem & 63;
      float pe = spe[tau];
      float lo = K[(size_t)((tau+192)&255)*16384 + ((eta+96)&127)*128 + ((om+96)&127)];
      float hi = K[(size_t)(tau+64)*16384 + (eta+32)*128 + (om+32)];
      sum += lo;
      float lp = lo+pe, hp = hi+pe;
      Lw[kap*BLKE + e] = lp;
      Hw[kap*BLKE + e] = hp;
      mnl=fminf(mnl,lp); mxl=fmaxf(mxl,lp);
      mnh=fminf(mnh,hp); mxh=fmaxf(mxh,hp);
    }
    sum = waveSum(sum); mnl=waveMinf(mnl); mxl=waveMaxf(mxl); mnh=waveMinf(mnh); mxh=waveMaxf(mxh);
    if ((tid&63)==0){ int w=tid>>6; sm[w]=sum; sm[4+w]=mnl; sm[8+w]=mxl; sm[12+w]=mnh; sm[16+w]=mxh; }
    __syncthreads();
    if (tid==0){
      float* o = pA + kap*1280 + bx*5;
      o[0] = sm[0]+sm[1]+sm[2]+sm[3];
      o[1] = fminf(fminf(sm[4],sm[5]),fminf(sm[6],sm[7]));
      o[2] = fmaxf(fmaxf(sm[8],sm[9]),fmaxf(sm[10],sm[11]));
      o[3] = fminf(fminf(sm[12],sm[13]),fminf(sm[14],sm[15]));
      o[4] = fmaxf(fmaxf(sm[16],sm[17]),fmaxf(sm[18],sm[19]));
    }
  } else if (bid < 640){
    int idx = (bid-512)*256 + tid;      // 32768 = 2*128*128
    int o = idx >> 14, r = idx & 16383;
    int t = r >> 7, s = r & 127;
    float acc = 0.f;
    int mlo = s-31; if (mlo < 0) mlo = 0;
    int mhi = s+31; if (mhi > 127) mhi = 127;
    for (int m = mlo; m <= mhi; m++) acc += mtx[t*128+m]*wave[o*63 + (s-m+31)];
    M[idx] = acc;
  } else {
    // one-time twiddle tables (double-precision trig once, not per FFT block)
    if (tid < 256){
      double ang = -PI2 * (double)tid / 256.0;
      twF[tid] = make_float2((float)cos(ang), (float)sin(ang));
    }
    if (tid < 64){
      double a2 = -PI2 * (double)tid / 128.0;
      twD[tid] = make_float2((float)cos(a2), (float)sin(a2));
      double a3 =  PI2 * (double)tid / 128.0;
      twI[tid] = make_float2((float)cos(a3), (float)sin(a3));
    }
  }
}

// ============ D2: pass B (0..511) || kTmp (512..1023) ========================
__global__ void __launch_bounds__(256) kD2(const float* __restrict__ feat,
                                           const float* __restrict__ M,
                                           float* __restrict__ tmp,
                                           const float* __restrict__ pA,
                                           const float* __restrict__ Lw,
                                           float* __restrict__ pB,
                                           const float* cw, const float* cb){
  __shared__ __align__(16) char smem[16640];
  __shared__ float sm[20], smo[4];
  int bid = blockIdx.x;
  int tid = threadIdx.x;
  if (bid < 512){
    int kap = bid >> 8, bx = bid & 255;
    float sum,mnl,mxl,mnh,mxh;
    bcastReduce5(pA,kap,sum,mnl,mxl,mnh,mxh,sm);
    float w = cw[0], b = cb[0];
    float s1 = w*(sum*(1.0f/BLKE)) + b;
    float a1 = s1*w, c1 = s1*b;
    float mx = (a1>=0.f) ? a1*mxl+c1 : a1*mnl+c1;
    float acc = 0.f;
    int base = kap*BLKE + bx*256 + tid;
    #pragma unroll
    for (int it = 0; it < 8; it++){
      float lp = Lw[base + it*65536];
      acc += expf(a1*lp + c1 - mx);
    }
    acc = waveSum(acc);
    if ((tid&63)==0) smo[tid>>6] = acc;
    __syncthreads();
    if (tid==0) pB[kap*256 + bx] = smo[0]+smo[1]+smo[2]+smo[3];
  } else {
    int e = bid - 512;                  // 512 : b(2) x tt(4) x xt(64)
    int b = e >> 8, tt = (e >> 6) & 3, xt = e & 63;
    float (*LF)[64] = (float(*)[64])smem;
    float (*LM)[32][33] = (float(*)[32][33])(smem + 8192);
    int xx = tid & 63, tq = tid >> 6;
    float acc0[8] = {}, acc1[8] = {};
    const float* fb = feat + (size_t)b*BLKE;
    for (int sb = 0; sb < 4; sb++){
      #pragma unroll
      for (int j = 0; j < 8; j++){
        int idx = tid + j*256; int s = idx >> 6, x = idx & 63;
        LF[s][x] = fb[(size_t)(sb*32+s)*4096 + xt*64 + x];
      }
      #pragma unroll
      for (int j = 0; j < 8; j++){
        int idx = tid + j*256; int o = idx >> 10, r = idx & 1023;
        int trow = r >> 5, s = r & 31;
        LM[o][trow][s] = M[o*16384 + (tt*32+trow)*128 + sb*32+s];
      }
      __syncthreads();
      for (int s = 0; s < 32; s++){
        float f = LF[s][xx];
        #pragma unroll
        for (int i = 0; i < 8; i++){
          acc0[i] += LM[0][tq*8+i][s]*f;
          acc1[i] += LM[1][tq*8+i][s]*f;
        }
      }
      __syncthreads();
    }
    #pragma unroll
    for (int i = 0; i < 8; i++){
      int t = tt*32 + tq*8 + i;
      tmp[(size_t)(0*2+b)*BLKE + (size_t)t*4096 + xt*64+xx] = acc0[i];
      tmp[(size_t)(1*2+b)*BLKE + (size_t)t*4096 + xt*64+xx] = acc1[i];
    }
  }
}

// ============ D3: pass C (0..511) || kF1 (512..2559) =========================
// FFT: 8 lines/block, pair ownership (l=tid>>5, ip=tid&31); zero-pad stage0
// fused at load; double stages (2,4) and (8,16) in registers; m=32 + full
// m=64 final in registers at the store (diff half * tw[0] as original).
__global__ void __launch_bounds__(256) kD3(const float* __restrict__ tmp,
                                           float2* __restrict__ Z2,
                                           const float* __restrict__ pA,
                                           const float* __restrict__ pB,
                                           const float* __restrict__ Lw,
                                           float* __restrict__ pC,
                                           const float* cw, const float* cb,
                                           const float2* __restrict__ twg){
  __shared__ __align__(16) char smem[17152];
  __shared__ float sm[20], smB[4], smo[4];
  int bid = blockIdx.x;
  int tid = threadIdx.x;
  if (bid < 512){
    int kap = bid >> 8, bx = bid & 255;
    float sum,mnl,mxl,mnh,mxh;
    bcastReduce5(pA,kap,sum,mnl,mxl,mnh,mxh,sm);
    float d1 = bcastSum256(pB + kap*256, smB);
    float w = cw[0], b = cb[0];
    float s1 = w*(sum*(1.0f/BLKE)) + b;
    float a1 = s1*w, c1 = s1*b;
    float mx = (a1>=0.f) ? a1*mxl+c1 : a1*mnl+c1;
    float invd = 1.0f/d1;
    float acc = 0.f;
    int base = kap*BLKE + bx*256 + tid;
    #pragma unroll
    for (int it = 0; it < 8; it++){
      float lp = Lw[base + it*65536];
      float p = expf(a1*lp + c1 - mx)*invd;
      acc += lp/(1.f + expf(-p));
    }
    acc = waveSum(acc);
    if ((tid&63)==0) smo[tid>>6] = acc;
    __syncthreads();
    if (tid==0) pC[kap*256 + bx] = smo[0]+smo[1]+smo[2]+smo[3];
  } else {
    int e = bid - 512;                  // 2048 : b(2) x 1024 line-groups(8)
    int b = e >> 10, bx = e & 1023;
    float2 (*bA)[130] = (float2(*)[130])smem;
    float2 (*bB)[130] = (float2(*)[130])(smem + 8320);
    float2* tw = (float2*)(smem + 16640);
    if (tid < 64) tw[tid] = twg[tid];
    int l = tid >> 5, ip = tid & 31;
    int line = bx*8 + l;
    int t = line >> 6, h = line & 63;
    const float* pc = tmp + (size_t)b*BLKE + (size_t)t*4096 + h*64;
    const float* ps = tmp + (size_t)(2+b)*BLKE + (size_t)t*4096 + h*64;
    float2 a0 = make_float2(pc[ip], ps[ip]);
    float2 a1 = make_float2(pc[ip+32], ps[ip+32]);
    __syncthreads();                    // tw visible
    // zero-pad stage 0: out[2i]=a, out[2i+1]=a*tw[i]
    bA[l][2*ip]    = a0;
    bA[l][2*ip+1]  = cmulf(a0, tw[ip]);
    bA[l][2*ip+64] = a1;
    bA[l][2*ip+65] = cmulf(a1, tw[ip+32]);
    __syncthreads();
    // double stage (2,4): bA -> bB
    {
      const int M = 2;
      int jA0 = ip & ~(M-1);
      int pA2 = ip + jA0;
      float2 u0 = bA[l][ip],    v0 = bA[l][ip+64];
      float2 u1 = bA[l][ip+32], v1 = bA[l][ip+96];
      float2 x0 = cadd(u0,v0);
      float2 x1 = cmulf(csub(u0,v0), tw[jA0]);
      float2 x2 = cadd(u1,v1);
      float2 x3 = cmulf(csub(u1,v1), tw[jA0+32]);
      int jB = pA2 & ~(2*M-1);
      bB[l][pA2+jB]       = cadd(x0,x2);
      bB[l][pA2+jB+2*M]   = cmulf(csub(x0,x2), tw[jB]);
      bB[l][pA2+M+jB]     = cadd(x1,x3);
      bB[l][pA2+M+jB+2*M] = cmulf(csub(x1,x3), tw[jB]);
    }
    __syncthreads();
    // double stage (8,16): bB -> bA
    {
      const int M = 8;
      int jA0 = ip & ~(M-1);
      int pA2 = ip + jA0;
      float2 u0 = bB[l][ip],    v0 = bB[l][ip+64];
      float2 u1 = bB[l][ip+32], v1 = bB[l][ip+96];
      float2 x0 = cadd(u0,v0);
      float2 x1 = cmulf(csub(u0,v0), tw[jA0]);
      float2 x2 = cadd(u1,v1);
      float2 x3 = cmulf(csub(u1,v1), tw[jA0+32]);
      int jB = pA2 & ~(2*M-1);
      bA[l][pA2+jB]       = cadd(x0,x2);
      bA[l][pA2+jB+2*M]   = cmulf(csub(x0,x2), tw[jB]);
      bA[l][pA2+M+jB]     = cadd(x1,x3);
      bA[l][pA2+M+jB+2*M] = cmulf(csub(x1,x3), tw[jB]);
    }
    __syncthreads();
    // stage m=32 + final m=64 (full width) in registers; store
    {
      float2 s0  = bA[l][ip],    s64 = bA[l][ip+64];
      float2 s32 = bA[l][ip+32], s96 = bA[l][ip+96];
      float2 v0  = cadd(s0,s64);                 // pos ip
      float2 v32 = cmulf(csub(s0,s64), tw[0]);   // pos ip+32
      float2 v64 = cadd(s32,s96);                // pos ip+64
      float2 v96 = cmulf(csub(s32,s96), tw[32]); // pos ip+96
      float2* outp = Z2 + (size_t)b*TCROP + (size_t)t*16384 + (size_t)h*128;
      outp[ip]    = cadd(v0, v64);
      outp[ip+64] = cmulf(csub(v0, v64), tw[0]);
      outp[ip+32] = cadd(v32, v96);
      outp[ip+96] = cmulf(csub(v32, v96), tw[0]);
    }
  }
}

// ============ D4: pass D (0..511) || kHf (512..2559) =========================
// FFT: pair ownership via q-loop (wl=tid&15, ip=(tid>>4)+16q); stage0 fused
// at load; double stages (2,4)/(8,16); m=32 + full m=64 final in registers.
// LDS: bA 16x130 (16640B) + bB 16x130 (16640B) + tw (512B) = 33792B.
__global__ void __launch_bounds__(256) kD4(float2* __restrict__ Z2,
                                           const float* __restrict__ pA,
                                           const float* __restrict__ pC,
                                           const float* __restrict__ Hw,
                                           float* __restrict__ pD,
                                           const float* cw, const float* cb,
                                           const float2* __restrict__ twg){
  __shared__ __align__(16) char smem[33792];
  __shared__ float sm[20], smC[4], smo[4];
  int bid = blockIdx.x;
  int tid = threadIdx.x;
  if (bid < 512){
    int kap = bid >> 8, bx = bid & 255;
    float sum,mnl,mxl,mnh,mxh;
    bcastReduce5(pA,kap,sum,mnl,mxl,mnh,mxh,sm);
    float sl2 = bcastSum256(pC + kap*256, smC);
    float w = cw[0], b = cb[0];
    float s2 = w*(sl2*(1.0f/BLKE)) + b;
    float a2 = s2*w, c2 = s2*b;
    float mx = (a2>=0.f) ? a2*mxh+c2 : a2*mnh+c2;
    float acc = 0.f;
    int base = kap*BLKE + bx*256 + tid;
    #pragma unroll
    for (int it = 0; it < 8; it++){
      float hp = Hw[base + it*65536];
      acc += expf(a2*hp + c2 - mx);
    }
    acc = waveSum(acc);
    if ((tid&63)==0) smo[tid>>6] = acc;
    __syncthreads();
    if (tid==0) pD[kap*256 + bx] = smo[0]+smo[1]+smo[2]+smo[3];
  } else {
    int e = bid - 512;                  // 2048 : b(2) x 1024
    int b = e >> 10, bx = e & 1023;
    float2 (*bA)[130] = (float2(*)[130])smem;
    float2 (*bB)[130] = (float2(*)[130])(smem + 16640);
    float2* tw = (float2*)(smem + 33280);
    if (tid < 64) tw[tid] = twg[tid];
    float2* Z = Z2 + (size_t)b*TCROP;
    int t = bx >> 3; int w0 = (bx & 7) << 4;
    size_t base = (size_t)t*16384 + w0;
    float2 l0, l1, l2, l3;
    {
      int i0 = tid;        l0 = Z[base + (size_t)(i0>>4)*128 + (i0&15)];
      int i1 = 256 + tid;  l1 = Z[base + (size_t)(i1>>4)*128 + (i1&15)];
      int i2 = 512 + tid;  l2 = Z[base + (size_t)(i2>>4)*128 + (i2&15)];
      int i3 = 768 + tid;  l3 = Z[base + (size_t)(i3>>4)*128 + (i3&15)];
    }
    __syncthreads();                    // tw visible
    {
      int i0 = tid;       int w_=i0&15, hh=i0>>4;
      bA[w_][2*hh] = l0;  bA[w_][2*hh+1] = cmulf(l0, tw[hh]);
      int i1 = 256+tid;   w_=i1&15; hh=i1>>4;
      bA[w_][2*hh] = l1;  bA[w_][2*hh+1] = cmulf(l1, tw[hh]);
      int i2 = 512+tid;   w_=i2&15; hh=i2>>4;
      bA[w_][2*hh] = l2;  bA[w_][2*hh+1] = cmulf(l2, tw[hh]);
      int i3 = 768+tid;   w_=i3&15; hh=i3>>4;
      bA[w_][2*hh] = l3;  bA[w_][2*hh+1] = cmulf(l3, tw[hh]);
    }
    __syncthreads();
    // double stage (2,4): bA -> bB
    #pragma unroll
    for (int q = 0; q < 2; q++){
      const int M = 2;
      int wl = tid & 15, ip = (tid >> 4) + 16*q;
      int jA0 = ip & ~(M-1);
      int pA2 = ip + jA0;
      float2 u0 = bA[wl][ip],    v0 = bA[wl][ip+64];
      float2 u1 = bA[wl][ip+32], v1 = bA[wl][ip+96];
      float2 x0 = cadd(u0,v0);
      float2 x1 = cmulf(csub(u0,v0), tw[jA0]);
      float2 x2 = cadd(u1,v1);
      float2 x3 = cmulf(csub(u1,v1), tw[jA0+32]);
      int jB = pA2 & ~(2*M-1);
      bB[wl][pA2+jB]       = cadd(x0,x2);
      bB[wl][pA2+jB+2*M]   = cmulf(csub(x0,x2), tw[jB]);
      bB[wl][pA2+M+jB]     = cadd(x1,x3);
      bB[wl][pA2+M+jB+2*M] = cmulf(csub(x1,x3), tw[jB]);
    }
    __syncthreads();
    // double stage (8,16): bB -> bA
    #pragma unroll
    for (int q = 0; q < 2; q++){
      const int M = 8;
      int wl = tid & 15, ip = (tid >> 4) + 16*q;
      int jA0 = ip & ~(M-1);
      int pA2 = ip + jA0;
      float2 u0 = bB[wl][ip],    v0 = bB[wl][ip+64];
      float2 u1 = bB[wl][ip+32], v1 = bB[wl][ip+96];
      float2 x0 = cadd(u0,v0);
      float2 x1 = cmulf(csub(u0,v0), tw[jA0]);
      float2 x2 = cadd(u1,v1);
      float2 x3 = cmulf(csub(u1,v1), tw[jA0+32]);
      int jB = pA2 & ~(2*M-1);
      bA[wl][pA2+jB]       = cadd(x0,x2);
      bA[wl][pA2+jB+2*M]   = cmulf(csub(x0,x2), tw[jB]);
      bA[wl][pA2+M+jB]     = cadd(x1,x3);
      bA[wl][pA2+M+jB+2*M] = cmulf(csub(x1,x3), tw[jB]);
    }
    __syncthreads();
    // stage m=32 + final m=64 (full width) in registers; store
    #pragma unroll
    for (int q = 0; q < 2; q++){
      int wl = tid & 15, ip = (tid >> 4) + 16*q;
      float2 s0  = bA[wl][ip],    s64 = bA[wl][ip+64];
      float2 s32 = bA[wl][ip+32], s96 = bA[wl][ip+96];
      float2 v0  = cadd(s0,s64);
      float2 v32 = cmulf(csub(s0,s64), tw[0]);
      float2 v64 = cadd(s32,s96);
      float2 v96 = cmulf(csub(s32,s96), tw[32]);
      Z[base + (size_t)(ip     )*128 + wl] = cadd(v0, v64);
      Z[base + (size_t)(ip + 64)*128 + wl] = cmulf(csub(v0, v64), tw[0]);
      Z[base + (size_t)(ip + 32)*128 + wl] = cadd(v32, v96);
      Z[base + (size_t)(ip + 96)*128 + wl] = cmulf(csub(v32, v96), tw[0]);
    }
  }
}

// ---------------- attention helpers ----------------
__device__ __forceinline__ float attnv(float v, float a, float c, float mx, float invd){
  float p = expf(a*v + c - mx)*invd;
  return v / (1.f + expf(-p));
}
// Branch-free wcAt (numerics verified: absmax 3.8e-06 unchanged).
__device__ __forceinline__ float2 wcAt(int t, int h, int w,
                                       const float* __restrict__ Kr, const float* __restrict__ Ki,
                                       const float* spe, const float* P){
  size_t off = (size_t)t*16384 + (size_t)h*128 + w;
  float kr = Kr[off], ki = Ki[off];
  bool center = (t>=64 && t<192) && (h>=32 && h<96) && (w>=32 && w<96);
  int tc = (t+64)&255, hc = (h+32)&127, wc = (w+32)&127;
  bool corner = (tc<128) && (hc<64) && (wc<64);
  bool act = center || corner;
  float pe = spe[(center ? (t-64) : tc) & 127];
  float A0 = center?P[4]:P[0],   C0 = center?P[5]:P[1];
  float M0 = center?P[6]:P[2],   I0 = center?P[7]:P[3];
  float A1 = center?P[12]:P[8],  C1 = center?P[13]:P[9];
  float M1 = center?P[14]:P[10], I1 = center?P[15]:P[11];
  float ox = attnv(kr+pe, A0, C0, M0, I0);
  float oy = attnv(ki+pe, A1, C1, M1, I1);
  return make_float2(act?ox:kr, act?oy:ki);
}

// ======== kP: finalize the 16 attention scalars once (1 block) ==============
__global__ void __launch_bounds__(256) kP(const float* __restrict__ pA,
                                          const float* __restrict__ pB,
                                          const float* __restrict__ pC,
                                          const float* __restrict__ pD,
                                          const float* cw, const float* cb,
                                          float* __restrict__ Pg){
  __shared__ float sm[20], smB[4], smC[4], smD[4];
  int tid = threadIdx.x;
  for (int kap = 0; kap < 2; kap++){
    if (kap) __syncthreads();
    float sum,mnl,mxl,mnh,mxh;
    bcastReduce5(pA,kap,sum,mnl,mxl,mnh,mxh,sm);
    float d1  = bcastSum256(pB + kap*256, smB);
    float sl2 = bcastSum256(pC + kap*256, smC);
    float d2  = bcastSum256(pD + kap*256, smD);
    if (tid==0){
      float w = cw[0], b = cb[0];
      float s1 = w*(sum*(1.0f/BLKE)) + b;
      float a1 = s1*w, c1 = s1*b;
      float mx1 = (a1>=0.f) ? a1*mxl+c1 : a1*mnl+c1;
      float s2 = w*(sl2*(1.0f/BLKE)) + b;
      float a2 = s2*w, c2 = s2*b;
      float mx2 = (a2>=0.f) ? a2*mxh+c2 : a2*mnh+c2;
      float* Q = Pg + kap*8;
      Q[0]=a1; Q[1]=c1; Q[2]=mx1; Q[3]=1.0f/d1;
      Q[4]=a2; Q[5]=c2; Q[6]=mx2; Q[7]=1.0f/d2;
    }
  }
}

// ======== kWc: materialize Wc volume (lean streaming, scalars from Pg) ======
__global__ void __launch_bounds__(256) kWc(const float* __restrict__ Kr,
                                           const float* __restrict__ Ki,
                                           const float* __restrict__ Pg,
                                           float2* __restrict__ Wc){
  __shared__ float spe[128];
  __shared__ float P[16];
  int tid = threadIdx.x;
  if (tid < 128) spe[tid] = sinf((float)tid);
  else if (tid < 144) P[tid-128] = Pg[tid-128];
  __syncthreads();
  #pragma unroll
  for (int q = 0; q < 4; q++){
    int idx = blockIdx.x*1024 + q*256 + tid;   // VOLE over 4096 blocks
    int t = idx >> 14, r = idx & 16383, h = r >> 7, w = r & 127;
    Wc[idx] = wcAt(t, h, w, Kr, Ki, spe, P);
  }
}

// -- fused fwd-T(256) + Wc multiply + 2x inv-T, radix-4 ----------------------
// 256 threads / 8 w-columns per block (grid 2048x2): same per-thread work and
// bit-identical column math as the 512-thread version, but 8 blocks/CU with
// 4-wave barrier groups instead of 4 blocks/CU with 8-wave groups.
__global__ void __launch_bounds__(256) kTfused(const float2* __restrict__ Z2,
                                               float2* __restrict__ U2,
                                               float2* __restrict__ V2,
                                               const float2* __restrict__ Wc,
                                               const float2* __restrict__ twg){
  __shared__ float2 buf[8][259];
  __shared__ float2 tw[256];
  int tid = threadIdx.x;
  tw[tid] = twg[tid];
  int b = blockIdx.y;
  int bid = blockIdx.x;                 // 2048 : 128 h x 16 w-tiles(8)
  int h = bid >> 4, w0 = (bid & 15) << 3;
  int wl = tid & 7, pq = tid >> 3;      // pq 0..31
  const float2* Z = Z2 + (size_t)b*TCROP;
  size_t gbase = (size_t)h*128 + w0 + wl;
  float2 d0 = Z[(size_t)(pq     )*16384 + gbase];
  float2 d1 = Z[(size_t)(pq + 32)*16384 + gbase];
  float2 d2 = Z[(size_t)(pq + 64)*16384 + gbase];
  float2 d3 = Z[(size_t)(pq + 96)*16384 + gbase];
  __syncthreads();                      // tw ready
  {
    float2 z0 = make_float2(d0.x+d2.x, d0.y+d2.y);
    float2 z2 = make_float2(d0.x-d2.x, d0.y-d2.y);
    float2 z1 = make_float2(d0.x+d2.y, d0.y-d2.x);
    float2 z3 = make_float2(d0.x-d2.y, d0.y+d2.x);
    buf[wl][pq]     = z0;
    buf[wl][pq+64]  = cmulf(z1, tw[pq]);
    buf[wl][pq+128] = cmulf(z2, tw[2*pq]);
    buf[wl][pq+192] = cmulf(z3, tw[3*pq]);
    int u = pq + 32;
    float2 y0 = make_float2(d1.x+d3.x, d1.y+d3.y);
    float2 y2 = make_float2(d1.x-d3.x, d1.y-d3.y);
    float2 y1 = make_float2(d1.x+d3.y, d1.y-d3.x);
    float2 y3 = make_float2(d1.x-d3.y, d1.y+d3.x);
    buf[wl][u]      = y0;
    buf[wl][u+64]   = cmulf(y1, tw[u]);
    buf[wl][u+128]  = cmulf(y2, tw[2*u]);
    buf[wl][u+192]  = cmulf(y3, tw[3*u]);
  }
  __syncthreads();
  #pragma unroll
  for (int st = 1; st < 4; st++){
    const int Q = 64 >> (2*st);
    const int f = 1 << (2*st);
    #pragma unroll
    for (int it = 0; it < 2; it++){
      int u = pq + 32*it;
      int j = u & (Q-1);
      int seg = u >> (6 - 2*st);
      int base = (seg << (8 - 2*st)) + j;
      float2 a0 = buf[wl][base];
      float2 a1 = buf[wl][base+Q];
      float2 a2 = buf[wl][base+2*Q];
      float2 a3 = buf[wl][base+3*Q];
      float2 t0 = make_float2(a0.x+a2.x, a0.y+a2.y);
      float2 t1 = make_float2(a0.x-a2.x, a0.y-a2.y);
      float2 t2 = make_float2(a1.x+a3.x, a1.y+a3.y);
      float2 t3 = make_float2(a1.x-a3.x, a1.y-a3.y);
      float2 z0 = make_float2(t0.x+t2.x, t0.y+t2.y);
      float2 z2 = make_float2(t0.x-t2.x, t0.y-t2.y);
      float2 z1 = make_float2(t1.x+t3.y, t1.y-t3.x);
      float2 z3 = make_float2(t1.x-t3.y, t1.y+t3.x);
      buf[wl][base]     = z0;
      buf[wl][base+Q]   = cmulf(z1, tw[f*j]);
      buf[wl][base+2*Q] = cmulf(z2, tw[2*f*j]);
      buf[wl][base+3*Q] = cmulf(z3, tw[3*f*j]);
    }
    __syncthreads();
  }
  float2 rg[8];
  #pragma unroll
  for (int q = 0; q < 8; q++) rg[q] = buf[wl][q*32 + pq];
  #pragma unroll
  for (int q = 0; q < 8; q++){
    int p = q*32 + pq;
    int kt = ((p&3)<<6) | (((p>>2)&3)<<4) | (((p>>4)&3)<<2) | ((p>>6)&3);
    float2 wc = Wc[(size_t)kt*16384 + (size_t)h*128 + w0 + wl];
    buf[wl][p] = cmulf(rg[q], wc);
  }
  __syncthreads();
  #pragma unroll
  for (int st = 0; st < 3; st++){
    const int Q = 1 << (2*st);
    const int f = 64 >> (2*st);
    #pragma unroll
    for (int it = 0; it < 2; it++){
      int u = pq + 32*it;
      int j = u & (Q-1);
      int seg = u >> (2*st);
      int base = (seg << (2*st + 2)) + j;
      float2 w1 = tw[f*j], w2 = tw[2*f*j], w3 = tw[3*f*j];
      float2 a0 = buf[wl][base];
      float2 r1 = buf[wl][base+Q];
      float2 r2 = buf[wl][base+2*Q];
      float2 r3 = buf[wl][base+3*Q];
      float2 b1 = make_float2(r1.x*w1.x + r1.y*w1.y, r1.y*w1.x - r1.x*w1.y);
      float2 b2 = make_float2(r2.x*w2.x + r2.y*w2.y, r2.y*w2.x - r2.x*w2.y);
      float2 b3 = make_float2(r3.x*w3.x + r3.y*w3.y, r3.y*w3.x - r3.x*w3.y);
      float2 t0 = make_float2(a0.x+b2.x, a0.y+b2.y);
      float2 t1 = make_float2(a0.x-b2.x, a0.y-b2.y);
      float2 t2 = make_float2(b1.x+b3.x, b1.y+b3.y);
      float2 t3 = make_float2(b1.x-b3.x, b1.y-b3.y);
      buf[wl][base]     = make_float2(t0.x+t2.x, t0.y+t2.y);
      buf[wl][base+Q]   = make_float2(t1.x-t3.y, t1.y+t3.x);
      buf[wl][base+2*Q] = make_float2(t0.x-t2.x, t0.y-t2.y);
      buf[wl][base+3*Q] = make_float2(t1.x+t3.y, t1.y-t3.x);
    }
    __syncthreads();
  }
  float2* Uo = U2 + (size_t)b*TCROP;
  #pragma unroll
  for (int uu = 0; uu < 2; uu++){
    int u = pq + 32*uu;
    float2 a0 = buf[wl][u];
    float2 r1 = buf[wl][u+64];
    float2 r2 = buf[wl][u+128];
    float2 r3 = buf[wl][u+192];
    float2 w1 = tw[u], w2 = tw[2*u], w3 = tw[3*u];
    float2 b1 = make_float2(r1.x*w1.x + r1.y*w1.y, r1.y*w1.x - r1.x*w1.y);
    float2 b2 = make_float2(r2.x*w2.x + r2.y*w2.y, r2.y*w2.x - r2.x*w2.y);
    float2 b3 = make_float2(r3.x*w3.x + r3.y*w3.y, r3.y*w3.x - r3.x*w3.y);
    float2 t0 = make_float2(a0.x+b2.x, a0.y+b2.y);
    float2 t1 = make_float2(a0.x-b2.x, a0.y-b2.y);
    float2 t2 = make_float2(b1.x+b3.x, b1.y+b3.y);
    float2 t3 = make_float2(b1.x-b3.x, b1.y-b3.y);
    Uo[(size_t)u*16384 + gbase]      = make_float2(t0.x+t2.x, t0.y+t2.y);
    Uo[(size_t)(u+64)*16384 + gbase] = make_float2(t1.x-t3.y, t1.y+t3.x);
  }
  #pragma unroll
  for (int q = 0; q < 8; q++){
    int p = q*32 + pq;
    int kt = ((p&3)<<6) | (((p>>2)&3)<<4) | (((p>>4)&3)<<2) | ((p>>6)&3);
    int tm = (256-kt)&255, hm = (128-h)&127, wm = (128-(w0+wl))&127;
    float2 wc = Wc[(size_t)tm*16384 + (size_t)hm*128 + wm];
    wc.y = -wc.y;
    buf[wl][p] = cmulf(rg[q], wc);
  }
  __syncthreads();
  #pragma unroll
  for (int st = 0; st < 3; st++){
    const int Q = 1 << (2*st);
    const int f = 64 >> (2*st);
    #pragma unroll
    for (int it = 0; it < 2; it++){
      int u = pq + 32*it;
      int j = u & (Q-1);
      int seg = u >> (2*st);
      int base = (seg << (2*st + 2)) + j;
      float2 w1 = tw[f*j], w2 = tw[2*f*j], w3 = tw[3*f*j];
      float2 a0 = buf[wl][base];
      float2 r1 = buf[wl][base+Q];
      float2 r2 = buf[wl][base+2*Q];
      float2 r3 = buf[wl][base+3*Q];
      float2 b1 = make_float2(r1.x*w1.x + r1.y*w1.y, r1.y*w1.x - r1.x*w1.y);
      float2 b2 = make_float2(r2.x*w2.x + r2.y*w2.y, r2.y*w2.x - r2.x*w2.y);
      float2 b3 = make_float2(r3.x*w3.x + r3.y*w3.y, r3.y*w3.x - r3.x*w3.y);
      float2 t0 = make_float2(a0.x+b2.x, a0.y+b2.y);
      float2 t1 = make_float2(a0.x-b2.x, a0.y-b2.y);
      float2 t2 = make_float2(b1.x+b3.x, b1.y+b3.y);
      float2 t3 = make_float2(b1.x-b3.x, b1.y-b3.y);
      buf[wl][base]     = make_float2(t0.x+t2.x, t0.y+t2.y);
      buf[wl][base+Q]   = make_float2(t1.x-t3.y, t1.y+t3.x);
      buf[wl][base+2*Q] = make_float2(t0.x-t2.x, t0.y-t2.y);
      buf[wl][base+3*Q] = make_float2(t1.x+t3.y, t1.y-t3.x);
    }
    __syncthreads();
  }
  float2* Vo = V2 + (size_t)b*TCROP;
  #pragma unroll
  for (int uu = 0; uu < 2; uu++){
    int u = pq + 32*uu;
    float2 a0 = buf[wl][u];
    float2 r1 = buf[wl][u+64];
    float2 r2 = buf[wl][u+128];
    float2 r3 = buf[wl][u+192];
    float2 w1 = tw[u], w2 = tw[2*u], w3 = tw[3*u];
    float2 b1 = make_float2(r1.x*w1.x + r1.y*w1.y, r1.y*w1.x - r1.x*w1.y);
    float2 b2 = make_float2(r2.x*w2.x + r2.y*w2.y, r2.y*w2.x - r2.x*w2.y);
    float2 b3 = make_float2(r3.x*w3.x + r3.y*w3.y, r3.y*w3.x - r3.x*w3.y);
    float2 t0 = make_float2(a0.x+b2.x, a0.y+b2.y);
    float2 t1 = make_float2(a0.x-b2.x, a0.y-b2.y);
    float2 t2 = make_float2(b1.x+b3.x, b1.y+b3.y);
    float2 t3 = make_float2(b1.x-b3.x, b1.y-b3.y);
    Vo[(size_t)u*16384 + gbase]      = make_float2(t0.x+t2.x, t0.y+t2.y);
    Vo[(size_t)(u+64)*16384 + gbase] = make_float2(t1.x-t3.y, t1.y+t3.x);
  }
}

// ---------------- H-axis inverse (N=128), 512 threads: grid (1024,b,uv) -----
__global__ void __launch_bounds__(512,8) kHi(float2* __restrict__ U2, float2* __restrict__ V2,
                                             const float2* __restrict__ twg){
  __shared__ float2 bA[16][130], bB[16][130], tw[64];
  int tid = threadIdx.x;
  if (tid < 64) tw[tid] = twg[tid];
  float2* Z = (blockIdx.z ? V2 : U2) + (size_t)blockIdx.y*TCROP;
  int bid = blockIdx.x;
  int t = bid >> 3; int w0 = (bid & 7) << 4;
  size_t base = (size_t)t*16384 + w0;
  int wl = tid & 15, ip = tid >> 4;    // ip in [0,32)
  float2 a0 = Z[base + (size_t)(ip     )*128 + wl];
  float2 b0 = Z[base + (size_t)(ip + 64)*128 + wl];
  float2 a1 = Z[base + (size_t)(ip + 32)*128 + wl];
  float2 b1 = Z[base + (size_t)(ip + 96)*128 + wl];
  __syncthreads();                      // tw visible
  bA[wl][2*ip]    = cadd(a0,b0);
  bA[wl][2*ip+1]  = cmulf(csub(a0,b0), tw[ip]);
  bA[wl][2*ip+64] = cadd(a1,b1);
  bA[wl][2*ip+65] = cmulf(csub(a1,b1), tw[ip+32]);
  __syncthreads();
  {
    const int M = 2;
    int jA0 = ip & ~(M-1);
    int pA  = ip + jA0;
    float2 u0 = bA[wl][ip],    v0 = bA[wl][ip+64];
    float2 u1 = bA[wl][ip+32], v1 = bA[wl][ip+96];
    float2 x0 = cadd(u0,v0);
    float2 x1 = cmulf(csub(u0,v0), tw[jA0]);
    float2 x2 = cadd(u1,v1);
    float2 x3 = cmulf(csub(u1,v1), tw[jA0+32]);
    int jB = pA & ~(2*M-1);
    bB[wl][pA+jB]       = cadd(x0,x2);
    bB[wl][pA+jB+2*M]   = cmulf(csub(x0,x2), tw[jB]);
    bB[wl][pA+M+jB]     = cadd(x1,x3);
    bB[wl][pA+M+jB+2*M] = cmulf(csub(x1,x3), tw[jB]);
  }
  __syncthreads();
  {
    const int M = 8;
    int jA0 = ip & ~(M-1);
    int pA  = ip + jA0;
    float2 u0 = bB[wl][ip],    v0 = bB[wl][ip+64];
    float2 u1 = bB[wl][ip+32], v1 = bB[wl][ip+96];
    float2 x0 = cadd(u0,v0);
    float2 x1 = cmulf(csub(u0,v0), tw[jA0]);
    float2 x2 = cadd(u1,v1);
    float2 x3 = cmulf(csub(u1,v1), tw[jA0+32]);
    int jB = pA & ~(2*M-1);
    bA[wl][pA+jB]       = cadd(x0,x2);
    bA[wl][pA+jB+2*M]   = cmulf(csub(x0,x2), tw[jB]);
    bA[wl][pA+M+jB]     = cadd(x1,x3);
    bA[wl][pA+M+jB+2*M] = cmulf(csub(x1,x3), tw[jB]);
  }
  __syncthreads();
  {
    float2 s0  = bA[wl][ip],    s64 = bA[wl][ip+64];
    float2 s32 = bA[wl][ip+32], s96 = bA[wl][ip+96];
    float2 v0  = cadd(s0,s64);                 // pos ip
    float2 v32 = cmulf(csub(s0,s64), tw[0]);   // pos ip+32
    float2 v64 = cadd(s32,s96);                // pos ip+64
    float2 v96 = cmulf(csub(s32,s96), tw[32]); // pos ip+96
    Z[base + (size_t)(ip     )*128 + wl] = cadd(v0,  v64);
    Z[base + (size_t)(ip + 32)*128 + wl] = cadd(v32, v96);
  }
}

// -- fused W-axis inverse + combine: per line FFT U then V; s=y*conj(v)*sc^2 --
__global__ void __launch_bounds__(256) kI3C(const float2* __restrict__ U2,
                                            const float2* __restrict__ V2,
                                            float* __restrict__ sq,
                                            const float2* __restrict__ twg){
  __shared__ float2 bA[8][130], bB[8][130], tw[64];
  int tid = threadIdx.x;
  if (tid < 64) tw[tid] = twg[tid];
  int b = blockIdx.y;
  int l = tid >> 5, ip = tid & 31;
  int line = blockIdx.x*8 + l;         // t<128, h<64
  int t = line >> 6, h = line & 63;
  size_t off = (size_t)b*TCROP + (size_t)t*16384 + (size_t)h*128;
  float2 ua0 = U2[off + ip],      ub0 = U2[off + ip + 64];
  float2 ua1 = U2[off + ip + 32], ub1 = U2[off + ip + 96];
  float2 va0 = V2[off + ip],      vb0 = V2[off + ip + 64];
  float2 va1 = V2[off + ip + 32], vb1 = V2[off + ip + 96];
  __syncthreads();                      // tw visible
  bA[l][2*ip]    = cadd(ua0,ub0);
  bA[l][2*ip+1]  = cmulf(csub(ua0,ub0), tw[ip]);
  bA[l][2*ip+64] = cadd(ua1,ub1);
  bA[l][2*ip+65] = cmulf(csub(ua1,ub1), tw[ip+32]);
  __syncthreads();
  {
    const int M = 2;
    int jA0 = ip & ~(M-1);
    int pA  = ip + jA0;
    float2 u0 = bA[l][ip],    v0 = bA[l][ip+64];
    float2 u1 = bA[l][ip+32], v1 = bA[l][ip+96];
    float2 x0 = cadd(u0,v0);
    float2 x1 = cmulf(csub(u0,v0), tw[jA0]);
    float2 x2 = cadd(u1,v1);
    float2 x3 = cmulf(csub(u1,v1), tw[jA0+32]);
    int jB = pA & ~(2*M-1);
    bB[l][pA+jB]       = cadd(x0,x2);
    bB[l][pA+jB+2*M]   = cmulf(csub(x0,x2), tw[jB]);
    bB[l][pA+M+jB]     = cadd(x1,x3);
    bB[l][pA+M+jB+2*M] = cmulf(csub(x1,x3), tw[jB]);
  }
  __syncthreads();
  {
    const int M = 8;
    int jA0 = ip & ~(M-1);
    int pA  = ip + jA0;
    float2 u0 = bB[l][ip],    v0 = bB[l][ip+64];
    float2 u1 = bB[l][ip+32], v1 = bB[l][ip+96];
    float2 x0 = cadd(u0,v0);
    float2 x1 = cmulf(csub(u0,v0), tw[jA0]);
    float2 x2 = cadd(u1,v1);
    float2 x3 = cmulf(csub(u1,v1), tw[jA0+32]);
    int jB = pA & ~(2*M-1);
    bA[l][pA+jB]       = cadd(x0,x2);
    bA[l][pA+jB+2*M]   = cmulf(csub(x0,x2), tw[jB]);
    bA[l][pA+M+jB]     = cadd(x1,x3);
    bA[l][pA+M+jB+2*M] = cmulf(csub(x1,x3), tw[jB]);
  }
  __syncthreads();
  float2 yA, yB;
  {
    float2 s0  = bA[l][ip],    s64 = bA[l][ip+64];
    float2 s32 = bA[l][ip+32], s96 = bA[l][ip+96];
    float2 v0  = cadd(s0,s64);
    float2 v32 = cmulf(csub(s0,s64), tw[0]);
    float2 v64 = cadd(s32,s96);
    float2 v96 = cmulf(csub(s32,s96), tw[32]);
    yA = cadd(v0,  v64);    // lane ip
    yB = cadd(v32, v96);    // lane ip+32
  }
  bB[l][2*ip]    = cadd(va0,vb0);
  bB[l][2*ip+1]  = cmulf(csub(va0,vb0), tw[ip]);
  bB[l][2*ip+64] = cadd(va1,vb1);
  bB[l][2*ip+65] = cmulf(csub(va1,vb1), tw[ip+32]);
  __syncthreads();
  {
    const int M = 2;
    int jA0 = ip & ~(M-1);
    int pA  = ip + jA0;
    float2 u0 = bB[l][ip],    v0 = bB[l][ip+64];
    float2 u1 = bB[l][ip+32], v1 = bB[l][ip+96];
    float2 x0 = cadd(u0,v0);
    float2 x1 = cmulf(csub(u0,v0), tw[jA0]);
    float2 x2 = cadd(u1,v1);
    float2 x3 = cmulf(csub(u1,v1), tw[jA0+32]);
    int jB = pA & ~(2*M-1);
    bA[l][pA+jB]       = cadd(x0,x2);
    bA[l][pA+jB+2*M]   = cmulf(csub(x0,x2), tw[jB]);
    bA[l][pA+M+jB]     = cadd(x1,x3);
    bA[l][pA+M+jB+2*M] = cmulf(csub(x1,x3), tw[jB]);
  }
  __syncthreads();
  {
    const int M = 8;
    int jA0 = ip & ~(M-1);
    int pA  = ip + jA0;
    float2 u0 = bA[l][ip],    v0 = bA[l][ip+64];
    float2 u1 = bA[l][ip+32], v1 = bA[l][ip+96];
    float2 x0 = cadd(u0,v0);
    float2 x1 = cmulf(csub(u0,v0), tw[jA0]);
    float2 x2 = cadd(u1,v1);
    float2 x3 = cmulf(csub(u1,v1), tw[jA0+32]);
    int jB = pA & ~(2*M-1);
    bB[l][pA+jB]       = cadd(x0,x2);
    bB[l][pA+jB+2*M]   = cmulf(csub(x0,x2), tw[jB]);
    bB[l][pA+M+jB]     = cadd(x1,x3);
    bB[l][pA+M+jB+2*M] = cmulf(csub(x1,x3), tw[jB]);
  }
  __syncthreads();
  {
    float2 s0  = bB[l][ip],    s64 = bB[l][ip+64];
    float2 s32 = bB[l][ip+32], s96 = bB[l][ip+96];
    float2 v0  = cadd(s0,s64);
    float2 v32 = cmulf(csub(s0,s64), tw[0]);
    float2 v64 = cadd(s32,s96);
    float2 v96 = cmulf(csub(s32,s96), tw[32]);
    float2 vA = cadd(v0,  v64);   // lane ip
    float2 vB = cadd(v32, v96);   // lane ip+32
    const float sc = 1.0f/(float)VOLE;
    const float sc2 = sc*sc;
    float2 sA = cmulf(yA, make_float2(vA.x, -vA.y));
    sA.x *= sc2; sA.y *= sc2;
    float magA = 0.5f*(sqrtf(sA.x*sA.x + sA.y*sA.y) + sA.x);
    magA = fmaxf(magA, 0.f);
    sq[(size_t)b*BLKE + (size_t)t*4096 + h*64 + ip] = sqrtf(magA);
    float2 sB = cmulf(yB, make_float2(vB.x, -vB.y));
    sB.x *= sc2; sB.y *= sc2;
    float magB = 0.5f*(sqrtf(sB.x*sB.x + sB.y*sB.y) + sB.x);
    magB = fmaxf(magB, 0.f);
    sq[(size_t)b*BLKE + (size_t)t*4096 + h*64 + ip + 32] = sqrtf(magB);
  }
}

// ---------------- out[b][t][x] = sum_m mtxi[t][m]*sq[b][m][x] ----------------
__global__ void __launch_bounds__(256) kOut(const float* __restrict__ sq,
                                            const float* __restrict__ mtxi,
                                            float* __restrict__ out){
  __shared__ float LF[32][64];
  __shared__ float LM[32][33];
  int b = blockIdx.z, tt = blockIdx.y, xt = blockIdx.x;
  int tid = threadIdx.x;
  int xx = tid & 63, tq = tid >> 6;
  float acc[8] = {};
  const float* fb = sq + (size_t)b*BLKE;
  for (int sb = 0; sb < 4; sb++){
    #pragma unroll
    for (int j = 0; j < 8; j++){
      int idx = tid + j*256; int s = idx >> 6, x = idx & 63;
      LF[s][x] = fb[(size_t)(sb*32+s)*4096 + xt*64 + x];
    }
    #pragma unroll
    for (int j = 0; j < 4; j++){
      int idx = tid + j*256; int trow = idx >> 5, s = idx & 31;
      LM[trow][s] = mtxi[(tt*32+trow)*128 + sb*32+s];
    }
    __syncthreads();
    for (int s = 0; s < 32; s++){
      float f = LF[s][xx];
      #pragma unroll
      for (int i = 0; i < 8; i++) acc[i] += LM[tq*8+i][s]*f;
    }
    __syncthreads();
  }
  #pragma unroll
  for (int i = 0; i < 8; i++){
    int t = tt*32 + tq*8 + i;
    out[(size_t)b*BLKE + (size_t)t*4096 + xt*64+xx] = acc[i];
  }
}

extern "C" void kernel_launch(void* const* d_in, const int* in_sizes, int n_in,
                              void* d_out, int out_size, void* d_ws, size_t ws_size,
                              hipStream_t stream){
  const float* feature = (const float*)d_in[0];
  const float* convW   = (const float*)d_in[1];
  const float* convB   = (const float*)d_in[2];
  const float* wave    = (const float*)d_in[3];
  const float* Kr      = (const float*)d_in[4];
  const float* Ki      = (const float*)d_in[5];
  const float* mtx     = (const float*)d_in[6];
  const float* mtxi    = (const float*)d_in[7];
  float* out = (float*)d_out;
  float* ws  = (float*)d_ws;

  float*  M    = ws;                         // 32768
  float*  pA   = ws + 32832;                 // 2560
  float*  pB   = ws + 35392;                 // 512
  float*  pC   = ws + 35904;                 // 512
  float*  pD   = ws + 36416;                 // 512
  float*  Pg   = ws + 37440;                 // 16 attention scalars
  float2* twF  = (float2*)(ws + 40960);      // 256 f2: forward N=256 twiddles
  float2* twD  = (float2*)(ws + 41472);      // 64 f2: forward N=128
  float2* twI  = (float2*)(ws + 41600);      // 64 f2: inverse N=128
  float*  tmp  = ws + 65536;                 // 2097152
  float*  sq   = ws + 65536 + 2097152;       // 1048576
  float2* Z2   = (float2*)(ws + 3211264);    // 2 * TCROP float2 (33.5 MB)
  float2* U2   = (float2*)(ws + 11599872);   // 2 * TCROP float2
  float2* V2   = (float2*)(ws + 19988480);   // 2 * TCROP float2
  float2* Wc   = (float2*)(ws + 28377088);   // VOLE float2 (33.5 MB)
  // Lw/Hw alias U2 (consumed by D2-D4 before kTfused writes U2)
  float*  Lw   = (float*)U2;                 // 2*BLKE
  float*  Hw   = ((float*)U2) + 1048576;     // 2*BLKE

  kD1 <<<641,  256, 0, stream>>>(mtx, wave, M, Kr, Ki, Lw, Hw, pA, twF, twD, twI);
  kD2 <<<1024, 256, 0, stream>>>(feature, M, tmp, pA, Lw, pB, convW, convB);
  kD3 <<<2560, 256, 0, stream>>>(tmp, Z2, pA, pB, Lw, pC, convW, convB, twD);
  kD4 <<<2560, 256, 0, stream>>>(Z2, pA, pC, Hw, pD, convW, convB, twD);
  kP  <<<1,    256, 0, stream>>>(pA, pB, pC, pD, convW, convB, Pg);
  kWc <<<4096, 256, 0, stream>>>(Kr, Ki, Pg, Wc);
  kTfused<<<dim3(2048,2), 256, 0, stream>>>(Z2, U2, V2, Wc, twF);
  kHi<<<dim3(1024,2,2), 512, 0, stream>>>(U2, V2, twI);
  kI3C<<<dim3(1024,2), 256, 0, stream>>>(U2, V2, sq, twI);
  kOut<<<dim3(64,4,2), 256, 0, stream>>>(sq, mtxi, out);
}

// Round 17
// 244.756 us; speedup vs baseline: 1.0927x; 1.0927x over previous
//
#include <hip/hip_runtime.h>

#define BLKE 524288      // 128*64*64
#define VOLE 4194304     // 256*128*128
#define TCROP 2097152    // 128*128*128 (t<128 compact complex volume)
#define PI2 6.283185307179586476925286766559

__device__ __forceinline__ float2 cmulf(float2 a, float2 b){
  return make_float2(a.x*b.x - a.y*b.y, a.x*b.y + a.y*b.x);
}
__device__ __forceinline__ float2 cadd(float2 a, float2 b){
  return make_float2(a.x+b.x, a.y+b.y);
}
__device__ __forceinline__ float2 csub(float2 a, float2 b){
  return make_float2(a.x-b.x, a.y-b.y);
}
__device__ __forceinline__ float waveSum(float v){
  #pragma unroll
  for (int o=32;o;o>>=1) v += __shfl_xor(v,o);
  return v;
}
__device__ __forceinline__ float waveMaxf(float v){
  #pragma unroll
  for (int o=32;o;o>>=1) v = fmaxf(v,__shfl_xor(v,o));
  return v;
}
__device__ __forceinline__ float waveMinf(float v){
  #pragma unroll
  for (int o=32;o;o>>=1) v = fminf(v,__shfl_xor(v,o));
  return v;
}

// Reduce pA[kappa][256][5] redundantly (identical FP order in every block).
__device__ __forceinline__ void bcastReduce5(const float* __restrict__ pA, int kap,
    float& sum, float& mnl, float& mxl, float& mnh, float& mxh, float* sm /*>=20*/){
  int tid = threadIdx.x;
  const float* q = pA + kap*1280 + tid*5;
  float s = q[0], a = q[1], b = q[2], c = q[3], d = q[4];
  s = waveSum(s); a = waveMinf(a); b = waveMaxf(b); c = waveMinf(c); d = waveMaxf(d);
  if ((tid&63)==0){ int w = tid>>6; sm[w]=s; sm[4+w]=a; sm[8+w]=b; sm[12+w]=c; sm[16+w]=d; }
  __syncthreads();
  sum = sm[0]+sm[1]+sm[2]+sm[3];
  mnl = fminf(fminf(sm[4],sm[5]),fminf(sm[6],sm[7]));
  mxl = fmaxf(fmaxf(sm[8],sm[9]),fmaxf(sm[10],sm[11]));
  mnh = fminf(fminf(sm[12],sm[13]),fminf(sm[14],sm[15]));
  mxh = fmaxf(fmaxf(sm[16],sm[17]),fmaxf(sm[18],sm[19]));
}

__device__ __forceinline__ float bcastSum256(const float* __restrict__ p, float* sm /*>=4*/){
  int tid = threadIdx.x;
  float s = waveSum(p[tid]);
  if ((tid&63)==0) sm[tid>>6] = s;
  __syncthreads();
  return sm[0]+sm[1]+sm[2]+sm[3];
}

// ============ D1: attention pass A (0..511) || kM (512..639) || tables (640) =
__global__ void __launch_bounds__(256) kD1(const float* __restrict__ mtx,
                                           const float* __restrict__ wave,
                                           float* __restrict__ M,
                                           const float* __restrict__ Kr,
                                           const float* __restrict__ Ki,
                                           float* __restrict__ Lw, float* __restrict__ Hw,
                                           float* __restrict__ pA,
                                           float2* __restrict__ twF,
                                           float2* __restrict__ twD,
                                           float2* __restrict__ twI){
  __shared__ float spe[128];
  __shared__ float sm[20];
  int bid = blockIdx.x;
  int tid = threadIdx.x;
  if (bid < 512){
    int kap = bid >> 8, bx = bid & 255;
    const float* K = kap ? Ki : Kr;
    if (tid < 128) spe[tid] = sinf((float)tid);
    __syncthreads();
    float sum=0.f, mnl=3.4e38f, mxl=-3.4e38f, mnh=3.4e38f, mxh=-3.4e38f;
    int base = bx*256 + tid;
    #pragma unroll
    for (int it = 0; it < 8; it++){
      int e = base + it*65536;
      int tau = e >> 12, rem = e & 4095, eta = rem >> 6, om = rem & 63;
      float pe = spe[tau];
      float lo = K[(size_t)((tau+192)&255)*16384 + ((eta+96)&127)*128 + ((om+96)&127)];
      float hi = K[(size_t)(tau+64)*16384 + (eta+32)*128 + (om+32)];
      sum += lo;
      float lp = lo+pe, hp = hi+pe;
      Lw[kap*BLKE + e] = lp;
      Hw[kap*BLKE + e] = hp;
      mnl=fminf(mnl,lp); mxl=fmaxf(mxl,lp);
      mnh=fminf(mnh,hp); mxh=fmaxf(mxh,hp);
    }
    sum = waveSum(sum); mnl=waveMinf(mnl); mxl=waveMaxf(mxl); mnh=waveMinf(mnh); mxh=waveMaxf(mxh);
    if ((tid&63)==0){ int w=tid>>6; sm[w]=sum; sm[4+w]=mnl; sm[8+w]=mxl; sm[12+w]=mnh; sm[16+w]=mxh; }
    __syncthreads();
    if (tid==0){
      float* o = pA + kap*1280 + bx*5;
      o[0] = sm[0]+sm[1]+sm[2]+sm[3];
      o[1] = fminf(fminf(sm[4],sm[5]),fminf(sm[6],sm[7]));
      o[2] = fmaxf(fmaxf(sm[8],sm[9]),fmaxf(sm[10],sm[11]));
      o[3] = fminf(fminf(sm[12],sm[13]),fminf(sm[14],sm[15]));
      o[4] = fmaxf(fmaxf(sm[16],sm[17]),fmaxf(sm[18],sm[19]));
    }
  } else if (bid < 640){
    int idx = (bid-512)*256 + tid;      // 32768 = 2*128*128
    int o = idx >> 14, r = idx & 16383;
    int t = r >> 7, s = r & 127;
    float acc = 0.f;
    int mlo = s-31; if (mlo < 0) mlo = 0;
    int mhi = s+31; if (mhi > 127) mhi = 127;
    for (int m = mlo; m <= mhi; m++) acc += mtx[t*128+m]*wave[o*63 + (s-m+31)];
    M[idx] = acc;
  } else {
    // one-time twiddle tables (double-precision trig once, not per FFT block)
    if (tid < 256){
      double ang = -PI2 * (double)tid / 256.0;
      twF[tid] = make_float2((float)cos(ang), (float)sin(ang));
    }
    if (tid < 64){
      double a2 = -PI2 * (double)tid / 128.0;
      twD[tid] = make_float2((float)cos(a2), (float)sin(a2));
      double a3 =  PI2 * (double)tid / 128.0;
      twI[tid] = make_float2((float)cos(a3), (float)sin(a3));
    }
  }
}

// ============ D2: pass B (0..511) || kTmp (512..1023) ========================
__global__ void __launch_bounds__(256) kD2(const float* __restrict__ feat,
                                           const float* __restrict__ M,
                                           float* __restrict__ tmp,
                                           const float* __restrict__ pA,
                                           const float* __restrict__ Lw,
                                           float* __restrict__ pB,
                                           const float* cw, const float* cb){
  __shared__ __align__(16) char smem[16640];
  __shared__ float sm[20], smo[4];
  int bid = blockIdx.x;
  int tid = threadIdx.x;
  if (bid < 512){
    int kap = bid >> 8, bx = bid & 255;
    float sum,mnl,mxl,mnh,mxh;
    bcastReduce5(pA,kap,sum,mnl,mxl,mnh,mxh,sm);
    float w = cw[0], b = cb[0];
    float s1 = w*(sum*(1.0f/BLKE)) + b;
    float a1 = s1*w, c1 = s1*b;
    float mx = (a1>=0.f) ? a1*mxl+c1 : a1*mnl+c1;
    float acc = 0.f;
    int base = kap*BLKE + bx*256 + tid;
    #pragma unroll
    for (int it = 0; it < 8; it++){
      float lp = Lw[base + it*65536];
      acc += expf(a1*lp + c1 - mx);
    }
    acc = waveSum(acc);
    if ((tid&63)==0) smo[tid>>6] = acc;
    __syncthreads();
    if (tid==0) pB[kap*256 + bx] = smo[0]+smo[1]+smo[2]+smo[3];
  } else {
    int e = bid - 512;                  // 512 : b(2) x tt(4) x xt(64)
    int b = e >> 8, tt = (e >> 6) & 3, xt = e & 63;
    float (*LF)[64] = (float(*)[64])smem;
    float (*LM)[32][33] = (float(*)[32][33])(smem + 8192);
    int xx = tid & 63, tq = tid >> 6;
    float acc0[8] = {}, acc1[8] = {};
    const float* fb = feat + (size_t)b*BLKE;
    for (int sb = 0; sb < 4; sb++){
      #pragma unroll
      for (int j = 0; j < 8; j++){
        int idx = tid + j*256; int s = idx >> 6, x = idx & 63;
        LF[s][x] = fb[(size_t)(sb*32+s)*4096 + xt*64 + x];
      }
      #pragma unroll
      for (int j = 0; j < 8; j++){
        int idx = tid + j*256; int o = idx >> 10, r = idx & 1023;
        int trow = r >> 5, s = r & 31;
        LM[o][trow][s] = M[o*16384 + (tt*32+trow)*128 + sb*32+s];
      }
      __syncthreads();
      for (int s = 0; s < 32; s++){
        float f = LF[s][xx];
        #pragma unroll
        for (int i = 0; i < 8; i++){
          acc0[i] += LM[0][tq*8+i][s]*f;
          acc1[i] += LM[1][tq*8+i][s]*f;
        }
      }
      __syncthreads();
    }
    #pragma unroll
    for (int i = 0; i < 8; i++){
      int t = tt*32 + tq*8 + i;
      tmp[(size_t)(0*2+b)*BLKE + (size_t)t*4096 + xt*64+xx] = acc0[i];
      tmp[(size_t)(1*2+b)*BLKE + (size_t)t*4096 + xt*64+xx] = acc1[i];
    }
  }
}

// ============ D3: pass C (0..511) || kF1 (512..2559) =========================
// FFT: 8 lines/block, pair ownership (l=tid>>5, ip=tid&31); zero-pad stage0
// fused at load; double stages (2,4) and (8,16) in registers; m=32 + full
// m=64 final in registers at the store (diff half * tw[0] as original).
__global__ void __launch_bounds__(256) kD3(const float* __restrict__ tmp,
                                           float2* __restrict__ Z2,
                                           const float* __restrict__ pA,
                                           const float* __restrict__ pB,
                                           const float* __restrict__ Lw,
                                           float* __restrict__ pC,
                                           const float* cw, const float* cb,
                                           const float2* __restrict__ twg){
  __shared__ __align__(16) char smem[17152];
  __shared__ float sm[20], smB[4], smo[4];
  int bid = blockIdx.x;
  int tid = threadIdx.x;
  if (bid < 512){
    int kap = bid >> 8, bx = bid & 255;
    float sum,mnl,mxl,mnh,mxh;
    bcastReduce5(pA,kap,sum,mnl,mxl,mnh,mxh,sm);
    float d1 = bcastSum256(pB + kap*256, smB);
    float w = cw[0], b = cb[0];
    float s1 = w*(sum*(1.0f/BLKE)) + b;
    float a1 = s1*w, c1 = s1*b;
    float mx = (a1>=0.f) ? a1*mxl+c1 : a1*mnl+c1;
    float invd = 1.0f/d1;
    float acc = 0.f;
    int base = kap*BLKE + bx*256 + tid;
    #pragma unroll
    for (int it = 0; it < 8; it++){
      float lp = Lw[base + it*65536];
      float p = expf(a1*lp + c1 - mx)*invd;
      acc += lp/(1.f + expf(-p));
    }
    acc = waveSum(acc);
    if ((tid&63)==0) smo[tid>>6] = acc;
    __syncthreads();
    if (tid==0) pC[kap*256 + bx] = smo[0]+smo[1]+smo[2]+smo[3];
  } else {
    int e = bid - 512;                  // 2048 : b(2) x 1024 line-groups(8)
    int b = e >> 10, bx = e & 1023;
    float2 (*bA)[130] = (float2(*)[130])smem;
    float2 (*bB)[130] = (float2(*)[130])(smem + 8320);
    float2* tw = (float2*)(smem + 16640);
    if (tid < 64) tw[tid] = twg[tid];
    int l = tid >> 5, ip = tid & 31;
    int line = bx*8 + l;
    int t = line >> 6, h = line & 63;
    const float* pc = tmp + (size_t)b*BLKE + (size_t)t*4096 + h*64;
    const float* ps = tmp + (size_t)(2+b)*BLKE + (size_t)t*4096 + h*64;
    float2 a0 = make_float2(pc[ip], ps[ip]);
    float2 a1 = make_float2(pc[ip+32], ps[ip+32]);
    __syncthreads();                    // tw visible
    // zero-pad stage 0: out[2i]=a, out[2i+1]=a*tw[i]
    bA[l][2*ip]    = a0;
    bA[l][2*ip+1]  = cmulf(a0, tw[ip]);
    bA[l][2*ip+64] = a1;
    bA[l][2*ip+65] = cmulf(a1, tw[ip+32]);
    __syncthreads();
    // double stage (2,4): bA -> bB
    {
      const int M = 2;
      int jA0 = ip & ~(M-1);
      int pA2 = ip + jA0;
      float2 u0 = bA[l][ip],    v0 = bA[l][ip+64];
      float2 u1 = bA[l][ip+32], v1 = bA[l][ip+96];
      float2 x0 = cadd(u0,v0);
      float2 x1 = cmulf(csub(u0,v0), tw[jA0]);
      float2 x2 = cadd(u1,v1);
      float2 x3 = cmulf(csub(u1,v1), tw[jA0+32]);
      int jB = pA2 & ~(2*M-1);
      bB[l][pA2+jB]       = cadd(x0,x2);
      bB[l][pA2+jB+2*M]   = cmulf(csub(x0,x2), tw[jB]);
      bB[l][pA2+M+jB]     = cadd(x1,x3);
      bB[l][pA2+M+jB+2*M] = cmulf(csub(x1,x3), tw[jB]);
    }
    __syncthreads();
    // double stage (8,16): bB -> bA
    {
      const int M = 8;
      int jA0 = ip & ~(M-1);
      int pA2 = ip + jA0;
      float2 u0 = bB[l][ip],    v0 = bB[l][ip+64];
      float2 u1 = bB[l][ip+32], v1 = bB[l][ip+96];
      float2 x0 = cadd(u0,v0);
      float2 x1 = cmulf(csub(u0,v0), tw[jA0]);
      float2 x2 = cadd(u1,v1);
      float2 x3 = cmulf(csub(u1,v1), tw[jA0+32]);
      int jB = pA2 & ~(2*M-1);
      bA[l][pA2+jB]       = cadd(x0,x2);
      bA[l][pA2+jB+2*M]   = cmulf(csub(x0,x2), tw[jB]);
      bA[l][pA2+M+jB]     = cadd(x1,x3);
      bA[l][pA2+M+jB+2*M] = cmulf(csub(x1,x3), tw[jB]);
    }
    __syncthreads();
    // stage m=32 + final m=64 (full width) in registers; store
    {
      float2 s0  = bA[l][ip],    s64 = bA[l][ip+64];
      float2 s32 = bA[l][ip+32], s96 = bA[l][ip+96];
      float2 v0  = cadd(s0,s64);                 // pos ip
      float2 v32 = cmulf(csub(s0,s64), tw[0]);   // pos ip+32
      float2 v64 = cadd(s32,s96);                // pos ip+64
      float2 v96 = cmulf(csub(s32,s96), tw[32]); // pos ip+96
      float2* outp = Z2 + (size_t)b*TCROP + (size_t)t*16384 + (size_t)h*128;
      outp[ip]    = cadd(v0, v64);
      outp[ip+64] = cmulf(csub(v0, v64), tw[0]);
      outp[ip+32] = cadd(v32, v96);
      outp[ip+96] = cmulf(csub(v32, v96), tw[0]);
    }
  }
}

// ============ D4: pass D (0..511) || kHf (512..2559) =========================
// FFT: pair ownership via q-loop (wl=tid&15, ip=(tid>>4)+16q); stage0 fused
// at load; double stages (2,4)/(8,16); m=32 + full m=64 final in registers.
// LDS: bA 16x130 (16640B) + bB 16x130 (16640B) + tw (512B) = 33792B.
__global__ void __launch_bounds__(256) kD4(float2* __restrict__ Z2,
                                           const float* __restrict__ pA,
                                           const float* __restrict__ pC,
                                           const float* __restrict__ Hw,
                                           float* __restrict__ pD,
                                           const float* cw, const float* cb,
                                           const float2* __restrict__ twg){
  __shared__ __align__(16) char smem[33792];
  __shared__ float sm[20], smC[4], smo[4];
  int bid = blockIdx.x;
  int tid = threadIdx.x;
  if (bid < 512){
    int kap = bid >> 8, bx = bid & 255;
    float sum,mnl,mxl,mnh,mxh;
    bcastReduce5(pA,kap,sum,mnl,mxl,mnh,mxh,sm);
    float sl2 = bcastSum256(pC + kap*256, smC);
    float w = cw[0], b = cb[0];
    float s2 = w*(sl2*(1.0f/BLKE)) + b;
    float a2 = s2*w, c2 = s2*b;
    float mx = (a2>=0.f) ? a2*mxh+c2 : a2*mnh+c2;
    float acc = 0.f;
    int base = kap*BLKE + bx*256 + tid;
    #pragma unroll
    for (int it = 0; it < 8; it++){
      float hp = Hw[base + it*65536];
      acc += expf(a2*hp + c2 - mx);
    }
    acc = waveSum(acc);
    if ((tid&63)==0) smo[tid>>6] = acc;
    __syncthreads();
    if (tid==0) pD[kap*256 + bx] = smo[0]+smo[1]+smo[2]+smo[3];
  } else {
    int e = bid - 512;                  // 2048 : b(2) x 1024
    int b = e >> 10, bx = e & 1023;
    float2 (*bA)[130] = (float2(*)[130])smem;
    float2 (*bB)[130] = (float2(*)[130])(smem + 16640);
    float2* tw = (float2*)(smem + 33280);
    if (tid < 64) tw[tid] = twg[tid];
    float2* Z = Z2 + (size_t)b*TCROP;
    int t = bx >> 3; int w0 = (bx & 7) << 4;
    size_t base = (size_t)t*16384 + w0;
    float2 l0, l1, l2, l3;
    {
      int i0 = tid;        l0 = Z[base + (size_t)(i0>>4)*128 + (i0&15)];
      int i1 = 256 + tid;  l1 = Z[base + (size_t)(i1>>4)*128 + (i1&15)];
      int i2 = 512 + tid;  l2 = Z[base + (size_t)(i2>>4)*128 + (i2&15)];
      int i3 = 768 + tid;  l3 = Z[base + (size_t)(i3>>4)*128 + (i3&15)];
    }
    __syncthreads();                    // tw visible
    {
      int i0 = tid;       int w_=i0&15, hh=i0>>4;
      bA[w_][2*hh] = l0;  bA[w_][2*hh+1] = cmulf(l0, tw[hh]);
      int i1 = 256+tid;   w_=i1&15; hh=i1>>4;
      bA[w_][2*hh] = l1;  bA[w_][2*hh+1] = cmulf(l1, tw[hh]);
      int i2 = 512+tid;   w_=i2&15; hh=i2>>4;
      bA[w_][2*hh] = l2;  bA[w_][2*hh+1] = cmulf(l2, tw[hh]);
      int i3 = 768+tid;   w_=i3&15; hh=i3>>4;
      bA[w_][2*hh] = l3;  bA[w_][2*hh+1] = cmulf(l3, tw[hh]);
    }
    __syncthreads();
    // double stage (2,4): bA -> bB
    #pragma unroll
    for (int q = 0; q < 2; q++){
      const int M = 2;
      int wl = tid & 15, ip = (tid >> 4) + 16*q;
      int jA0 = ip & ~(M-1);
      int pA2 = ip + jA0;
      float2 u0 = bA[wl][ip],    v0 = bA[wl][ip+64];
      float2 u1 = bA[wl][ip+32], v1 = bA[wl][ip+96];
      float2 x0 = cadd(u0,v0);
      float2 x1 = cmulf(csub(u0,v0), tw[jA0]);
      float2 x2 = cadd(u1,v1);
      float2 x3 = cmulf(csub(u1,v1), tw[jA0+32]);
      int jB = pA2 & ~(2*M-1);
      bB[wl][pA2+jB]       = cadd(x0,x2);
      bB[wl][pA2+jB+2*M]   = cmulf(csub(x0,x2), tw[jB]);
      bB[wl][pA2+M+jB]     = cadd(x1,x3);
      bB[wl][pA2+M+jB+2*M] = cmulf(csub(x1,x3), tw[jB]);
    }
    __syncthreads();
    // double stage (8,16): bB -> bA
    #pragma unroll
    for (int q = 0; q < 2; q++){
      const int M = 8;
      int wl = tid & 15, ip = (tid >> 4) + 16*q;
      int jA0 = ip & ~(M-1);
      int pA2 = ip + jA0;
      float2 u0 = bB[wl][ip],    v0 = bB[wl][ip+64];
      float2 u1 = bB[wl][ip+32], v1 = bB[wl][ip+96];
      float2 x0 = cadd(u0,v0);
      float2 x1 = cmulf(csub(u0,v0), tw[jA0]);
      float2 x2 = cadd(u1,v1);
      float2 x3 = cmulf(csub(u1,v1), tw[jA0+32]);
      int jB = pA2 & ~(2*M-1);
      bA[wl][pA2+jB]       = cadd(x0,x2);
      bA[wl][pA2+jB+2*M]   = cmulf(csub(x0,x2), tw[jB]);
      bA[wl][pA2+M+jB]     = cadd(x1,x3);
      bA[wl][pA2+M+jB+2*M] = cmulf(csub(x1,x3), tw[jB]);
    }
    __syncthreads();
    // stage m=32 + final m=64 (full width) in registers; store
    #pragma unroll
    for (int q = 0; q < 2; q++){
      int wl = tid & 15, ip = (tid >> 4) + 16*q;
      float2 s0  = bA[wl][ip],    s64 = bA[wl][ip+64];
      float2 s32 = bA[wl][ip+32], s96 = bA[wl][ip+96];
      float2 v0  = cadd(s0,s64);
      float2 v32 = cmulf(csub(s0,s64), tw[0]);
      float2 v64 = cadd(s32,s96);
      float2 v96 = cmulf(csub(s32,s96), tw[32]);
      Z[base + (size_t)(ip     )*128 + wl] = cadd(v0, v64);
      Z[base + (size_t)(ip + 64)*128 + wl] = cmulf(csub(v0, v64), tw[0]);
      Z[base + (size_t)(ip + 32)*128 + wl] = cadd(v32, v96);
      Z[base + (size_t)(ip + 96)*128 + wl] = cmulf(csub(v32, v96), tw[0]);
    }
  }
}

// ---------------- attention helpers ----------------
__device__ __forceinline__ float attnv(float v, float a, float c, float mx, float invd){
  float p = expf(a*v + c - mx)*invd;
  return v / (1.f + expf(-p));
}
// Branch-free wcAt (numerics verified: absmax 3.8e-06 unchanged).
__device__ __forceinline__ float2 wcAt(int t, int h, int w,
                                       const float* __restrict__ Kr, const float* __restrict__ Ki,
                                       const float* spe, const float* P){
  size_t off = (size_t)t*16384 + (size_t)h*128 + w;
  float kr = Kr[off], ki = Ki[off];
  bool center = (t>=64 && t<192) && (h>=32 && h<96) && (w>=32 && w<96);
  int tc = (t+64)&255, hc = (h+32)&127, wc = (w+32)&127;
  bool corner = (tc<128) && (hc<64) && (wc<64);
  bool act = center || corner;
  float pe = spe[(center ? (t-64) : tc) & 127];
  float A0 = center?P[4]:P[0],   C0 = center?P[5]:P[1];
  float M0 = center?P[6]:P[2],   I0 = center?P[7]:P[3];
  float A1 = center?P[12]:P[8],  C1 = center?P[13]:P[9];
  float M1 = center?P[14]:P[10], I1 = center?P[15]:P[11];
  float ox = attnv(kr+pe, A0, C0, M0, I0);
  float oy = attnv(ki+pe, A1, C1, M1, I1);
  return make_float2(act?ox:kr, act?oy:ki);
}

// ======== kP: finalize the 16 attention scalars once (1 block) ==============
__global__ void __launch_bounds__(256) kP(const float* __restrict__ pA,
                                          const float* __restrict__ pB,
                                          const float* __restrict__ pC,
                                          const float* __restrict__ pD,
                                          const float* cw, const float* cb,
                                          float* __restrict__ Pg){
  __shared__ float sm[20], smB[4], smC[4], smD[4];
  int tid = threadIdx.x;
  for (int kap = 0; kap < 2; kap++){
    if (kap) __syncthreads();
    float sum,mnl,mxl,mnh,mxh;
    bcastReduce5(pA,kap,sum,mnl,mxl,mnh,mxh,sm);
    float d1  = bcastSum256(pB + kap*256, smB);
    float sl2 = bcastSum256(pC + kap*256, smC);
    float d2  = bcastSum256(pD + kap*256, smD);
    if (tid==0){
      float w = cw[0], b = cb[0];
      float s1 = w*(sum*(1.0f/BLKE)) + b;
      float a1 = s1*w, c1 = s1*b;
      float mx1 = (a1>=0.f) ? a1*mxl+c1 : a1*mnl+c1;
      float s2 = w*(sl2*(1.0f/BLKE)) + b;
      float a2 = s2*w, c2 = s2*b;
      float mx2 = (a2>=0.f) ? a2*mxh+c2 : a2*mnh+c2;
      float* Q = Pg + kap*8;
      Q[0]=a1; Q[1]=c1; Q[2]=mx1; Q[3]=1.0f/d1;
      Q[4]=a2; Q[5]=c2; Q[6]=mx2; Q[7]=1.0f/d2;
    }
  }
}

// ======== kWc: materialize Wc volume (lean streaming, scalars from Pg) ======
__global__ void __launch_bounds__(256) kWc(const float* __restrict__ Kr,
                                           const float* __restrict__ Ki,
                                           const float* __restrict__ Pg,
                                           float2* __restrict__ Wc){
  __shared__ float spe[128];
  __shared__ float P[16];
  int tid = threadIdx.x;
  if (tid < 128) spe[tid] = sinf((float)tid);
  else if (tid < 144) P[tid-128] = Pg[tid-128];
  __syncthreads();
  #pragma unroll
  for (int q = 0; q < 4; q++){
    int idx = blockIdx.x*1024 + q*256 + tid;   // VOLE over 4096 blocks
    int t = idx >> 14, r = idx & 16383, h = r >> 7, w = r & 127;
    Wc[idx] = wcAt(t, h, w, Kr, Ki, spe, P);
  }
}

// -- fused fwd-T(256) + Wc multiply + 2x inv-T, radix-4 ----------------------
// Round-8 form (VGPR 40, proven 50.1-50.6 us).
__global__ void __launch_bounds__(512) kTfused(const float2* __restrict__ Z2,
                                               float2* __restrict__ U2,
                                               float2* __restrict__ V2,
                                               const float2* __restrict__ Wc,
                                               const float2* __restrict__ twg){
  __shared__ float2 buf[16][259];
  __shared__ float2 tw[256];
  int tid = threadIdx.x;
  if (tid < 256) tw[tid] = twg[tid];
  int b = blockIdx.y;
  int bid = blockIdx.x;                 // 1024 : 128 h x 8 w-tiles(16)
  int h = bid >> 3, w0 = (bid & 7) << 4;
  int wl = tid & 15, pq = tid >> 4;     // pq 0..31
  const float2* Z = Z2 + (size_t)b*TCROP;
  size_t gbase = (size_t)h*128 + w0 + wl;
  float2 d0 = Z[(size_t)(pq     )*16384 + gbase];
  float2 d1 = Z[(size_t)(pq + 32)*16384 + gbase];
  float2 d2 = Z[(size_t)(pq + 64)*16384 + gbase];
  float2 d3 = Z[(size_t)(pq + 96)*16384 + gbase];
  __syncthreads();                      // tw ready
  {
    float2 z0 = make_float2(d0.x+d2.x, d0.y+d2.y);
    float2 z2 = make_float2(d0.x-d2.x, d0.y-d2.y);
    float2 z1 = make_float2(d0.x+d2.y, d0.y-d2.x);
    float2 z3 = make_float2(d0.x-d2.y, d0.y+d2.x);
    buf[wl][pq]     = z0;
    buf[wl][pq+64]  = cmulf(z1, tw[pq]);
    buf[wl][pq+128] = cmulf(z2, tw[2*pq]);
    buf[wl][pq+192] = cmulf(z3, tw[3*pq]);
    int u = pq + 32;
    float2 y0 = make_float2(d1.x+d3.x, d1.y+d3.y);
    float2 y2 = make_float2(d1.x-d3.x, d1.y-d3.y);
    float2 y1 = make_float2(d1.x+d3.y, d1.y-d3.x);
    float2 y3 = make_float2(d1.x-d3.y, d1.y+d3.x);
    buf[wl][u]      = y0;
    buf[wl][u+64]   = cmulf(y1, tw[u]);
    buf[wl][u+128]  = cmulf(y2, tw[2*u]);
    buf[wl][u+192]  = cmulf(y3, tw[3*u]);
  }
  __syncthreads();
  #pragma unroll
  for (int st = 1; st < 4; st++){
    const int Q = 64 >> (2*st);
    const int f = 1 << (2*st);
    #pragma unroll
    for (int it = 0; it < 2; it++){
      int u = pq + 32*it;
      int j = u & (Q-1);
      int seg = u >> (6 - 2*st);
      int base = (seg << (8 - 2*st)) + j;
      float2 a0 = buf[wl][base];
      float2 a1 = buf[wl][base+Q];
      float2 a2 = buf[wl][base+2*Q];
      float2 a3 = buf[wl][base+3*Q];
      float2 t0 = make_float2(a0.x+a2.x, a0.y+a2.y);
      float2 t1 = make_float2(a0.x-a2.x, a0.y-a2.y);
      float2 t2 = make_float2(a1.x+a3.x, a1.y+a3.y);
      float2 t3 = make_float2(a1.x-a3.x, a1.y-a3.y);
      float2 z0 = make_float2(t0.x+t2.x, t0.y+t2.y);
      float2 z2 = make_float2(t0.x-t2.x, t0.y-t2.y);
      float2 z1 = make_float2(t1.x+t3.y, t1.y-t3.x);
      float2 z3 = make_float2(t1.x-t3.y, t1.y+t3.x);
      buf[wl][base]     = z0;
      buf[wl][base+Q]   = cmulf(z1, tw[f*j]);
      buf[wl][base+2*Q] = cmulf(z2, tw[2*f*j]);
      buf[wl][base+3*Q] = cmulf(z3, tw[3*f*j]);
    }
    __syncthreads();
  }
  float2 rg[8];
  #pragma unroll
  for (int q = 0; q < 8; q++) rg[q] = buf[wl][q*32 + pq];
  #pragma unroll
  for (int q = 0; q < 8; q++){
    int p = q*32 + pq;
    int kt = ((p&3)<<6) | (((p>>2)&3)<<4) | (((p>>4)&3)<<2) | ((p>>6)&3);
    float2 wc = Wc[(size_t)kt*16384 + (size_t)h*128 + w0 + wl];
    buf[wl][p] = cmulf(rg[q], wc);
  }
  __syncthreads();
  #pragma unroll
  for (int st = 0; st < 3; st++){
    const int Q = 1 << (2*st);
    const int f = 64 >> (2*st);
    #pragma unroll
    for (int it = 0; it < 2; it++){
      int u = pq + 32*it;
      int j = u & (Q-1);
      int seg = u >> (2*st);
      int base = (seg << (2*st + 2)) + j;
      float2 w1 = tw[f*j], w2 = tw[2*f*j], w3 = tw[3*f*j];
      float2 a0 = buf[wl][base];
      float2 r1 = buf[wl][base+Q];
      float2 r2 = buf[wl][base+2*Q];
      float2 r3 = buf[wl][base+3*Q];
      float2 b1 = make_float2(r1.x*w1.x + r1.y*w1.y, r1.y*w1.x - r1.x*w1.y);
      float2 b2 = make_float2(r2.x*w2.x + r2.y*w2.y, r2.y*w2.x - r2.x*w2.y);
      float2 b3 = make_float2(r3.x*w3.x + r3.y*w3.y, r3.y*w3.x - r3.x*w3.y);
      float2 t0 = make_float2(a0.x+b2.x, a0.y+b2.y);
      float2 t1 = make_float2(a0.x-b2.x, a0.y-b2.y);
      float2 t2 = make_float2(b1.x+b3.x, b1.y+b3.y);
      float2 t3 = make_float2(b1.x-b3.x, b1.y-b3.y);
      buf[wl][base]     = make_float2(t0.x+t2.x, t0.y+t2.y);
      buf[wl][base+Q]   = make_float2(t1.x-t3.y, t1.y+t3.x);
      buf[wl][base+2*Q] = make_float2(t0.x-t2.x, t0.y-t2.y);
      buf[wl][base+3*Q] = make_float2(t1.x+t3.y, t1.y-t3.x);
    }
    __syncthreads();
  }
  float2* Uo = U2 + (size_t)b*TCROP;
  #pragma unroll
  for (int uu = 0; uu < 2; uu++){
    int u = pq + 32*uu;
    float2 a0 = buf[wl][u];
    float2 r1 = buf[wl][u+64];
    float2 r2 = buf[wl][u+128];
    float2 r3 = buf[wl][u+192];
    float2 w1 = tw[u], w2 = tw[2*u], w3 = tw[3*u];
    float2 b1 = make_float2(r1.x*w1.x + r1.y*w1.y, r1.y*w1.x - r1.x*w1.y);
    float2 b2 = make_float2(r2.x*w2.x + r2.y*w2.y, r2.y*w2.x - r2.x*w2.y);
    float2 b3 = make_float2(r3.x*w3.x + r3.y*w3.y, r3.y*w3.x - r3.x*w3.y);
    float2 t0 = make_float2(a0.x+b2.x, a0.y+b2.y);
    float2 t1 = make_float2(a0.x-b2.x, a0.y-b2.y);
    float2 t2 = make_float2(b1.x+b3.x, b1.y+b3.y);
    float2 t3 = make_float2(b1.x-b3.x, b1.y-b3.y);
    Uo[(size_t)u*16384 + gbase]      = make_float2(t0.x+t2.x, t0.y+t2.y);
    Uo[(size_t)(u+64)*16384 + gbase] = make_float2(t1.x-t3.y, t1.y+t3.x);
  }
  #pragma unroll
  for (int q = 0; q < 8; q++){
    int p = q*32 + pq;
    int kt = ((p&3)<<6) | (((p>>2)&3)<<4) | (((p>>4)&3)<<2) | ((p>>6)&3);
    int tm = (256-kt)&255, hm = (128-h)&127, wm = (128-(w0+wl))&127;
    float2 wc = Wc[(size_t)tm*16384 + (size_t)hm*128 + wm];
    wc.y = -wc.y;
    buf[wl][p] = cmulf(rg[q], wc);
  }
  __syncthreads();
  #pragma unroll
  for (int st = 0; st < 3; st++){
    const int Q = 1 << (2*st);
    const int f = 64 >> (2*st);
    #pragma unroll
    for (int it = 0; it < 2; it++){
      int u = pq + 32*it;
      int j = u & (Q-1);
      int seg = u >> (2*st);
      int base = (seg << (2*st + 2)) + j;
      float2 w1 = tw[f*j], w2 = tw[2*f*j], w3 = tw[3*f*j];
      float2 a0 = buf[wl][base];
      float2 r1 = buf[wl][base+Q];
      float2 r2 = buf[wl][base+2*Q];
      float2 r3 = buf[wl][base+3*Q];
      float2 b1 = make_float2(r1.x*w1.x + r1.y*w1.y, r1.y*w1.x - r1.x*w1.y);
      float2 b2 = make_float2(r2.x*w2.x + r2.y*w2.y, r2.y*w2.x - r2.x*w2.y);
      float2 b3 = make_float2(r3.x*w3.x + r3.y*w3.y, r3.y*w3.x - r3.x*w3.y);
      float2 t0 = make_float2(a0.x+b2.x, a0.y+b2.y);
      float2 t1 = make_float2(a0.x-b2.x, a0.y-b2.y);
      float2 t2 = make_float2(b1.x+b3.x, b1.y+b3.y);
      float2 t3 = make_float2(b1.x-b3.x, b1.y-b3.y);
      buf[wl][base]     = make_float2(t0.x+t2.x, t0.y+t2.y);
      buf[wl][base+Q]   = make_float2(t1.x-t3.y, t1.y+t3.x);
      buf[wl][base+2*Q] = make_float2(t0.x-t2.x, t0.y-t2.y);
      buf[wl][base+3*Q] = make_float2(t1.x+t3.y, t1.y-t3.x);
    }
    __syncthreads();
  }
  float2* Vo = V2 + (size_t)b*TCROP;
  #pragma unroll
  for (int uu = 0; uu < 2; uu++){
    int u = pq + 32*uu;
    float2 a0 = buf[wl][u];
    float2 r1 = buf[wl][u+64];
    float2 r2 = buf[wl][u+128];
    float2 r3 = buf[wl][u+192];
    float2 w1 = tw[u], w2 = tw[2*u], w3 = tw[3*u];
    float2 b1 = make_float2(r1.x*w1.x + r1.y*w1.y, r1.y*w1.x - r1.x*w1.y);
    float2 b2 = make_float2(r2.x*w2.x + r2.y*w2.y, r2.y*w2.x - r2.x*w2.y);
    float2 b3 = make_float2(r3.x*w3.x + r3.y*w3.y, r3.y*w3.x - r3.x*w3.y);
    float2 t0 = make_float2(a0.x+b2.x, a0.y+b2.y);
    float2 t1 = make_float2(a0.x-b2.x, a0.y-b2.y);
    float2 t2 = make_float2(b1.x+b3.x, b1.y+b3.y);
    float2 t3 = make_float2(b1.x-b3.x, b1.y-b3.y);
    Vo[(size_t)u*16384 + gbase]      = make_float2(t0.x+t2.x, t0.y+t2.y);
    Vo[(size_t)(u+64)*16384 + gbase] = make_float2(t1.x-t3.y, t1.y+t3.x);
  }
}

// ---------------- H-axis inverse (N=128), 512 threads: grid (1024,b,uv) -----
__global__ void __launch_bounds__(512,8) kHi(float2* __restrict__ U2, float2* __restrict__ V2,
                                             const float2* __restrict__ twg){
  __shared__ float2 bA[16][130], bB[16][130], tw[64];
  int tid = threadIdx.x;
  if (tid < 64) tw[tid] = twg[tid];
  float2* Z = (blockIdx.z ? V2 : U2) + (size_t)blockIdx.y*TCROP;
  int bid = blockIdx.x;
  int t = bid >> 3; int w0 = (bid & 7) << 4;
  size_t base = (size_t)t*16384 + w0;
  int wl = tid & 15, ip = tid >> 4;    // ip in [0,32)
  float2 a0 = Z[base + (size_t)(ip     )*128 + wl];
  float2 b0 = Z[base + (size_t)(ip + 64)*128 + wl];
  float2 a1 = Z[base + (size_t)(ip + 32)*128 + wl];
  float2 b1 = Z[base + (size_t)(ip + 96)*128 + wl];
  __syncthreads();                      // tw visible
  bA[wl][2*ip]    = cadd(a0,b0);
  bA[wl][2*ip+1]  = cmulf(csub(a0,b0), tw[ip]);
  bA[wl][2*ip+64] = cadd(a1,b1);
  bA[wl][2*ip+65] = cmulf(csub(a1,b1), tw[ip+32]);
  __syncthreads();
  {
    const int M = 2;
    int jA0 = ip & ~(M-1);
    int pA  = ip + jA0;
    float2 u0 = bA[wl][ip],    v0 = bA[wl][ip+64];
    float2 u1 = bA[wl][ip+32], v1 = bA[wl][ip+96];
    float2 x0 = cadd(u0,v0);
    float2 x1 = cmulf(csub(u0,v0), tw[jA0]);
    float2 x2 = cadd(u1,v1);
    float2 x3 = cmulf(csub(u1,v1), tw[jA0+32]);
    int jB = pA & ~(2*M-1);
    bB[wl][pA+jB]       = cadd(x0,x2);
    bB[wl][pA+jB+2*M]   = cmulf(csub(x0,x2), tw[jB]);
    bB[wl][pA+M+jB]     = cadd(x1,x3);
    bB[wl][pA+M+jB+2*M] = cmulf(csub(x1,x3), tw[jB]);
  }
  __syncthreads();
  {
    const int M = 8;
    int jA0 = ip & ~(M-1);
    int pA  = ip + jA0;
    float2 u0 = bB[wl][ip],    v0 = bB[wl][ip+64];
    float2 u1 = bB[wl][ip+32], v1 = bB[wl][ip+96];
    float2 x0 = cadd(u0,v0);
    float2 x1 = cmulf(csub(u0,v0), tw[jA0]);
    float2 x2 = cadd(u1,v1);
    float2 x3 = cmulf(csub(u1,v1), tw[jA0+32]);
    int jB = pA & ~(2*M-1);
    bA[wl][pA+jB]       = cadd(x0,x2);
    bA[wl][pA+jB+2*M]   = cmulf(csub(x0,x2), tw[jB]);
    bA[wl][pA+M+jB]     = cadd(x1,x3);
    bA[wl][pA+M+jB+2*M] = cmulf(csub(x1,x3), tw[jB]);
  }
  __syncthreads();
  {
    float2 s0  = bA[wl][ip],    s64 = bA[wl][ip+64];
    float2 s32 = bA[wl][ip+32], s96 = bA[wl][ip+96];
    float2 v0  = cadd(s0,s64);                 // pos ip
    float2 v32 = cmulf(csub(s0,s64), tw[0]);   // pos ip+32
    float2 v64 = cadd(s32,s96);                // pos ip+64
    float2 v96 = cmulf(csub(s32,s96), tw[32]); // pos ip+96
    Z[base + (size_t)(ip     )*128 + wl] = cadd(v0,  v64);
    Z[base + (size_t)(ip + 32)*128 + wl] = cadd(v32, v96);
  }
}

// -- fused W-axis inverse + combine: per line FFT U then V; s=y*conj(v)*sc^2 --
__global__ void __launch_bounds__(256) kI3C(const float2* __restrict__ U2,
                                            const float2* __restrict__ V2,
                                            float* __restrict__ sq,
                                            const float2* __restrict__ twg){
  __shared__ float2 bA[8][130], bB[8][130], tw[64];
  int tid = threadIdx.x;
  if (tid < 64) tw[tid] = twg[tid];
  int b = blockIdx.y;
  int l = tid >> 5, ip = tid & 31;
  int line = blockIdx.x*8 + l;         // t<128, h<64
  int t = line >> 6, h = line & 63;
  size_t off = (size_t)b*TCROP + (size_t)t*16384 + (size_t)h*128;
  float2 ua0 = U2[off + ip],      ub0 = U2[off + ip + 64];
  float2 ua1 = U2[off + ip + 32], ub1 = U2[off + ip + 96];
  float2 va0 = V2[off + ip],      vb0 = V2[off + ip + 64];
  float2 va1 = V2[off + ip + 32], vb1 = V2[off + ip + 96];
  __syncthreads();                      // tw visible
  bA[l][2*ip]    = cadd(ua0,ub0);
  bA[l][2*ip+1]  = cmulf(csub(ua0,ub0), tw[ip]);
  bA[l][2*ip+64] = cadd(ua1,ub1);
  bA[l][2*ip+65] = cmulf(csub(ua1,ub1), tw[ip+32]);
  __syncthreads();
  {
    const int M = 2;
    int jA0 = ip & ~(M-1);
    int pA  = ip + jA0;
    float2 u0 = bA[l][ip],    v0 = bA[l][ip+64];
    float2 u1 = bA[l][ip+32], v1 = bA[l][ip+96];
    float2 x0 = cadd(u0,v0);
    float2 x1 = cmulf(csub(u0,v0), tw[jA0]);
    float2 x2 = cadd(u1,v1);
    float2 x3 = cmulf(csub(u1,v1), tw[jA0+32]);
    int jB = pA & ~(2*M-1);
    bB[l][pA+jB]       = cadd(x0,x2);
    bB[l][pA+jB+2*M]   = cmulf(csub(x0,x2), tw[jB]);
    bB[l][pA+M+jB]     = cadd(x1,x3);
    bB[l][pA+M+jB+2*M] = cmulf(csub(x1,x3), tw[jB]);
  }
  __syncthreads();
  {
    const int M = 8;
    int jA0 = ip & ~(M-1);
    int pA  = ip + jA0;
    float2 u0 = bB[l][ip],    v0 = bB[l][ip+64];
    float2 u1 = bB[l][ip+32], v1 = bB[l][ip+96];
    float2 x0 = cadd(u0,v0);
    float2 x1 = cmulf(csub(u0,v0), tw[jA0]);
    float2 x2 = cadd(u1,v1);
    float2 x3 = cmulf(csub(u1,v1), tw[jA0+32]);
    int jB = pA & ~(2*M-1);
    bA[l][pA+jB]       = cadd(x0,x2);
    bA[l][pA+jB+2*M]   = cmulf(csub(x0,x2), tw[jB]);
    bA[l][pA+M+jB]     = cadd(x1,x3);
    bA[l][pA+M+jB+2*M] = cmulf(csub(x1,x3), tw[jB]);
  }
  __syncthreads();
  float2 yA, yB;
  {
    float2 s0  = bA[l][ip],    s64 = bA[l][ip+64];
    float2 s32 = bA[l][ip+32], s96 = bA[l][ip+96];
    float2 v0  = cadd(s0,s64);
    float2 v32 = cmulf(csub(s0,s64), tw[0]);
    float2 v64 = cadd(s32,s96);
    float2 v96 = cmulf(csub(s32,s96), tw[32]);
    yA = cadd(v0,  v64);    // lane ip
    yB = cadd(v32, v96);    // lane ip+32
  }
  bB[l][2*ip]    = cadd(va0,vb0);
  bB[l][2*ip+1]  = cmulf(csub(va0,vb0), tw[ip]);
  bB[l][2*ip+64] = cadd(va1,vb1);
  bB[l][2*ip+65] = cmulf(csub(va1,vb1), tw[ip+32]);
  __syncthreads();
  {
    const int M = 2;
    int jA0 = ip & ~(M-1);
    int pA  = ip + jA0;
    float2 u0 = bB[l][ip],    v0 = bB[l][ip+64];
    float2 u1 = bB[l][ip+32], v1 = bB[l][ip+96];
    float2 x0 = cadd(u0,v0);
    float2 x1 = cmulf(csub(u0,v0), tw[jA0]);
    float2 x2 = cadd(u1,v1);
    float2 x3 = cmulf(csub(u1,v1), tw[jA0+32]);
    int jB = pA & ~(2*M-1);
    bA[l][pA+jB]       = cadd(x0,x2);
    bA[l][pA+jB+2*M]   = cmulf(csub(x0,x2), tw[jB]);
    bA[l][pA+M+jB]     = cadd(x1,x3);
    bA[l][pA+M+jB+2*M] = cmulf(csub(x1,x3), tw[jB]);
  }
  __syncthreads();
  {
    const int M = 8;
    int jA0 = ip & ~(M-1);
    int pA  = ip + jA0;
    float2 u0 = bA[l][ip],    v0 = bA[l][ip+64];
    float2 u1 = bA[l][ip+32], v1 = bA[l][ip+96];
    float2 x0 = cadd(u0,v0);
    float2 x1 = cmulf(csub(u0,v0), tw[jA0]);
    float2 x2 = cadd(u1,v1);
    float2 x3 = cmulf(csub(u1,v1), tw[jA0+32]);
    int jB = pA & ~(2*M-1);
    bB[l][pA+jB]       = cadd(x0,x2);
    bB[l][pA+jB+2*M]   = cmulf(csub(x0,x2), tw[jB]);
    bB[l][pA+M+jB]     = cadd(x1,x3);
    bB[l][pA+M+jB+2*M] = cmulf(csub(x1,x3), tw[jB]);
  }
  __syncthreads();
  {
    float2 s0  = bB[l][ip],    s64 = bB[l][ip+64];
    float2 s32 = bB[l][ip+32], s96 = bB[l][ip+96];
    float2 v0  = cadd(s0,s64);
    float2 v32 = cmulf(csub(s0,s64), tw[0]);
    float2 v64 = cadd(s32,s96);
    float2 v96 = cmulf(csub(s32,s96), tw[32]);
    float2 vA = cadd(v0,  v64);   // lane ip
    float2 vB = cadd(v32, v96);   // lane ip+32
    const float sc = 1.0f/(float)VOLE;
    const float sc2 = sc*sc;
    float2 sA = cmulf(yA, make_float2(vA.x, -vA.y));
    sA.x *= sc2; sA.y *= sc2;
    float magA = 0.5f*(sqrtf(sA.x*sA.x + sA.y*sA.y) + sA.x);
    magA = fmaxf(magA, 0.f);
    sq[(size_t)b*BLKE + (size_t)t*4096 + h*64 + ip] = sqrtf(magA);
    float2 sB = cmulf(yB, make_float2(vB.x, -vB.y));
    sB.x *= sc2; sB.y *= sc2;
    float magB = 0.5f*(sqrtf(sB.x*sB.x + sB.y*sB.y) + sB.x);
    magB = fmaxf(magB, 0.f);
    sq[(size_t)b*BLKE + (size_t)t*4096 + h*64 + ip + 32] = sqrtf(magB);
  }
}

// ---------------- out[b][t][x] = sum_m mtxi[t][m]*sq[b][m][x] ----------------
__global__ void __launch_bounds__(256) kOut(const float* __restrict__ sq,
                                            const float* __restrict__ mtxi,
                                            float* __restrict__ out){
  __shared__ float LF[32][64];
  __shared__ float LM[32][33];
  int b = blockIdx.z, tt = blockIdx.y, xt = blockIdx.x;
  int tid = threadIdx.x;
  int xx = tid & 63, tq = tid >> 6;
  float acc[8] = {};
  const float* fb = sq + (size_t)b*BLKE;
  for (int sb = 0; sb < 4; sb++){
    #pragma unroll
    for (int j = 0; j < 8; j++){
      int idx = tid + j*256; int s = idx >> 6, x = idx & 63;
      LF[s][x] = fb[(size_t)(sb*32+s)*4096 + xt*64 + x];
    }
    #pragma unroll
    for (int j = 0; j < 4; j++){
      int idx = tid + j*256; int trow = idx >> 5, s = idx & 31;
      LM[trow][s] = mtxi[(tt*32+trow)*128 + sb*32+s];
    }
    __syncthreads();
    for (int s = 0; s < 32; s++){
      float f = LF[s][xx];
      #pragma unroll
      for (int i = 0; i < 8; i++) acc[i] += LM[tq*8+i][s]*f;
    }
    __syncthreads();
  }
  #pragma unroll
  for (int i = 0; i < 8; i++){
    int t = tt*32 + tq*8 + i;
    out[(size_t)b*BLKE + (size_t)t*4096 + xt*64+xx] = acc[i];
  }
}

extern "C" void kernel_launch(void* const* d_in, const int* in_sizes, int n_in,
                              void* d_out, int out_size, void* d_ws, size_t ws_size,
                              hipStream_t stream){
  const float* feature = (const float*)d_in[0];
  const float* convW   = (const float*)d_in[1];
  const float* convB   = (const float*)d_in[2];
  const float* wave    = (const float*)d_in[3];
  const float* Kr      = (const float*)d_in[4];
  const float* Ki      = (const float*)d_in[5];
  const float* mtx     = (const float*)d_in[6];
  const float* mtxi    = (const float*)d_in[7];
  float* out = (float*)d_out;
  float* ws  = (float*)d_ws;

  float*  M    = ws;                         // 32768
  float*  pA   = ws + 32832;                 // 2560
  float*  pB   = ws + 35392;                 // 512
  float*  pC   = ws + 35904;                 // 512
  float*  pD   = ws + 36416;                 // 512
  float*  Pg   = ws + 37440;                 // 16 attention scalars
  float2* twF  = (float2*)(ws + 40960);      // 256 f2: forward N=256 twiddles
  float2* twD  = (float2*)(ws + 41472);      // 64 f2: forward N=128
  float2* twI  = (float2*)(ws + 41600);      // 64 f2: inverse N=128
  float*  tmp  = ws + 65536;                 // 2097152
  float*  sq   = ws + 65536 + 2097152;       // 1048576
  float2* Z2   = (float2*)(ws + 3211264);    // 2 * TCROP float2 (33.5 MB)
  float2* U2   = (float2*)(ws + 11599872);   // 2 * TCROP float2
  float2* V2   = (float2*)(ws + 19988480);   // 2 * TCROP float2
  float2* Wc   = (float2*)(ws + 28377088);   // VOLE float2 (33.5 MB)
  // Lw/Hw alias U2 (consumed by D2-D4 before kTfused writes U2)
  float*  Lw   = (float*)U2;                 // 2*BLKE
  float*  Hw   = ((float*)U2) + 1048576;     // 2*BLKE

  kD1 <<<641,  256, 0, stream>>>(mtx, wave, M, Kr, Ki, Lw, Hw, pA, twF, twD, twI);
  kD2 <<<1024, 256, 0, stream>>>(feature, M, tmp, pA, Lw, pB, convW, convB);
  kD3 <<<2560, 256, 0, stream>>>(tmp, Z2, pA, pB, Lw, pC, convW, convB, twD);
  kD4 <<<2560, 256, 0, stream>>>(Z2, pA, pC, Hw, pD, convW, convB, twD);
  kP  <<<1,    256, 0, stream>>>(pA, pB, pC, pD, convW, convB, Pg);
  kWc <<<4096, 256, 0, stream>>>(Kr, Ki, Pg, Wc);
  kTfused<<<dim3(1024,2), 512, 0, stream>>>(Z2, U2, V2, Wc, twF);
  kHi<<<dim3(1024,2,2), 512, 0, stream>>>(U2, V2, twI);
  kI3C<<<dim3(1024,2), 256, 0, stream>>>(U2, V2, sq, twI);
  kOut<<<dim3(64,4,2), 256, 0, stream>>>(sq, mtxi, out);
}